// Round 13
// baseline (1858.204 us; speedup 1.0000x reference)
//
#include <hip/hip_runtime.h>
#include <math.h>

// ---------------- problem constants ----------------
#define PH   4
#define CHN  8
#define ZT   8
#define ZE   6          // effective z slices: z in [1,7)
#define HG   320
#define WG   320
#define HW2  102400     // 320*320
#define NKP  4096
#define LSTR 321        // LDS line stride (pad +1)
#define FBCAP 131072u   // fallback list capacity (entries)

constexpr float GAMMA_C = 0.1f;
constexpr float TAU_C   = 0.2f;
constexpr float EPS_C   = 0.01f;
constexpr float INV_N   = 1.0f / 786432.0f;   // PH*CHN*ZE*NKP
#define TWO_PI_F 6.28318530717958647692f

// W5^j = e^{-2*pi*i*j/5}
constexpr float W5R[5] = { 1.f,  0.30901699f, -0.80901699f, -0.80901699f,  0.30901699f};
constexpr float W5I[5] = { 0.f, -0.95105652f, -0.58778525f,  0.58778525f,  0.95105652f};

// ---------------- complex helpers ----------------
__device__ __forceinline__ float2 cmul(float2 a, float2 b){
  return make_float2(a.x*b.x - a.y*b.y, a.x*b.y + a.y*b.x);
}
__device__ __forceinline__ void cmac(float2& d, float2 a, float2 b){
  d.x = fmaf(a.x, b.x, fmaf(-a.y, b.y, d.x));
  d.y = fmaf(a.x, b.y, fmaf( a.y, b.x, d.y));
}

__device__ __forceinline__ void corners(float gy, float gx, int& y0, int& x0, int& y1, int& x1,
                                        float& w00, float& w01, float& w10, float& w11){
  float y0f = floorf(gy), x0f = floorf(gx);
  float wy = gy - y0f, wx = gx - x0f;
  y0 = (int)y0f; x0 = (int)x0f;
  y1 = min(y0 + 1, HG - 1); x1 = min(x0 + 1, WG - 1);
  w00 = (1.f - wy) * (1.f - wx);
  w01 = (1.f - wy) * wx;
  w10 = wy * (1.f - wx);
  w11 = wy * wx;
}

__device__ __forceinline__ void traj_to_grid(float ty, float tx, float& gy, float& gx){
  gy = fminf(fmaxf((ty / TWO_PI_F + 0.5f) * 320.f, 0.f), 319.f);
  gx = fminf(fmaxf((tx / TWO_PI_F + 0.5f) * 320.f, 0.f), 319.f);
}

// ---------------- in-register 320-pt FFT: one wave per line, N = 5 x 64 ----------------
// (verified rounds 5-12). Lane l stores X[5*br6(l)+r]; un-permuted via LDS seg.
struct FT {
  float2 t1, t2, t3, t4;
  float2 tw0, tw1, tw2, tw3, tw4;
  int br5, lane;
};

__device__ __forceinline__ FT ft_init(){
  FT f; int l = (int)(threadIdx.x & 63); f.lane = l;
  sincosf(-TWO_PI_F * (float)l * (1.0f/320.0f), &f.t1.y, &f.t1.x);
  f.t2 = cmul(f.t1, f.t1); f.t3 = cmul(f.t2, f.t1); f.t4 = cmul(f.t2, f.t2);
  sincosf(-TWO_PI_F * (float)(l & 31) * (1.0f/64.0f), &f.tw0.y, &f.tw0.x);
  sincosf(-TWO_PI_F * (float)(l & 15) * (1.0f/32.0f), &f.tw1.y, &f.tw1.x);
  sincosf(-TWO_PI_F * (float)(l &  7) * (1.0f/16.0f), &f.tw2.y, &f.tw2.x);
  sincosf(-TWO_PI_F * (float)(l &  3) * (1.0f/ 8.0f), &f.tw3.y, &f.tw3.x);
  f.tw4 = (l & 1) ? make_float2(0.f, -1.f) : make_float2(1.f, 0.f);
  int br = ((l&1)<<5) | ((l&2)<<3) | ((l&4)<<1) | ((l&8)>>1) | ((l&16)>>3) | ((l&32)>>5);
  f.br5 = 5 * br;
  return f;
}

template<int H>
__device__ __forceinline__ void bfly(float2& v, float2 tw, int lane){
  float px = __shfl_xor(v.x, H, 64);
  float py = __shfl_xor(v.y, H, 64);
  bool up = (lane & H) != 0;
  float ax = up ? px : v.x, ay = up ? py : v.y;
  float bx = up ? v.x : px, by = up ? v.y : py;
  float dx = ax - bx,  dy = ay - by;
  float mx = fmaf(dx, tw.x, -dy * tw.y);
  float my = fmaf(dx, tw.y,  dy * tw.x);
  v.x = up ? mx : (ax + bx);
  v.y = up ? my : (ay + by);
}

__device__ __forceinline__ void fft320w(const float2 a[5], const FT& f, float2* __restrict__ seg){
  float2 z[5];
  #pragma unroll
  for (int r = 0; r < 5; r++){
    float2 acc = a[0];
    #pragma unroll
    for (int q = 1; q < 5; q++){
      const int j = (q * r) % 5;
      cmac(acc, a[q], make_float2(W5R[j], W5I[j]));
    }
    z[r] = acc;
  }
  z[1] = cmul(z[1], f.t1); z[2] = cmul(z[2], f.t2);
  z[3] = cmul(z[3], f.t3); z[4] = cmul(z[4], f.t4);
  #pragma unroll
  for (int r = 0; r < 5; r++){
    float2 v = z[r];
    bfly<32>(v, f.tw0, f.lane);
    bfly<16>(v, f.tw1, f.lane);
    bfly< 8>(v, f.tw2, f.lane);
    bfly< 4>(v, f.tw3, f.lane);
    bfly< 2>(v, f.tw4, f.lane);
    {
      float px = __shfl_xor(v.x, 1, 64);
      float py = __shfl_xor(v.y, 1, 64);
      bool up = (f.lane & 1) != 0;
      float ax = up ? px : v.x, ay = up ? py : v.y;
      float bx = up ? v.x : px, by = up ? v.y : py;
      v.x = up ? (ax - bx) : (ax + bx);
      v.y = up ? (ay - by) : (ay + by);
    }
    seg[f.br5 + r] = v;
  }
}

// ---------------- k-point x-sorting (once per call; traj constant across iterations) --------
__global__ __launch_bounds__(256) void k_khist(const float* __restrict__ traj, unsigned* __restrict__ xhist){
  int gid = blockIdx.x * 256 + threadIdx.x;
  if (gid >= PH * NKP) return;
  int p = gid >> 12, k = gid & (NKP - 1);
  float gy, gx;
  traj_to_grid(traj[(p * 2 + 0) * NKP + k], traj[(p * 2 + 1) * NKP + k], gy, gx);
  atomicAdd(&xhist[p * WG + (int)floorf(gx)], 1u);
}

__global__ void k_kscan(const unsigned* __restrict__ xhist, unsigned* __restrict__ xcur,
                        unsigned* __restrict__ xbnd){
  int p = threadIdx.x;
  if (p < PH){
    unsigned acc = 0;
    for (int b = 0; b < WG; b++){ xcur[p * WG + b] = acc; xbnd[p * (WG + 1) + b] = acc; acc += xhist[p * WG + b]; }
    xbnd[p * (WG + 1) + WG] = acc;
  }
}

__global__ __launch_bounds__(256) void k_kperm(const float* __restrict__ traj, unsigned* __restrict__ xcur,
                                               float4* __restrict__ permx){
  int gid = blockIdx.x * 256 + threadIdx.x;
  if (gid >= PH * NKP) return;
  int p = gid >> 12, k = gid & (NKP - 1);
  float gy, gx;
  traj_to_grid(traj[(p * 2 + 0) * NKP + k], traj[(p * 2 + 1) * NKP + k], gy, gx);
  unsigned sx = atomicAdd(&xcur[p * WG + (int)floorf(gx)], 1u);
  permx[p * NKP + sx] = make_float4(__uint_as_float((unsigned)k), gy, gx, 0.f);
}

// ---------------- kernels ----------------
__global__ __launch_bounds__(256) void k_init(const float2* __restrict__ img0, float2* __restrict__ x, int n){
  int i = blockIdx.x * 256 + threadIdx.x;
  if (i < n){
    float2 v = img0[i];
    v.x = isnan(v.x) ? 0.f : fminf(fmaxf(v.x, -3.4028235e38f), 3.4028235e38f);
    v.y = isnan(v.y) ? 0.f : fminf(fmaxf(v.y, -3.4028235e38f), 3.4028235e38f);
    x[i] = v;
  }
}

// fused: warped = bilinear-warp(x, mvf); gtv = conj(TV-grad(x)); also zeroes dmax/fbcnt
__global__ __launch_bounds__(256) void k_warp_tv(const float2* __restrict__ x, const float* __restrict__ mvf,
                                                 float2* __restrict__ warped, float2* __restrict__ gtv,
                                                 unsigned int* __restrict__ dmax, unsigned int* __restrict__ fbcnt){
  if (blockIdx.x == 0 && threadIdx.x == 0){ *dmax = 0u; *fbcnt = 0u; }
  int gid = blockIdx.x * 256 + threadIdx.x;          // over PH*ZE*HW2
  int hw = gid % HW2;
  int pz = gid / HW2;
  int zz = pz % ZE, p = pz / ZE, z = zz + 1;
  int h = hw / WG, w = hw - h * WG;
  const float* mv = mvf + ((size_t)(p * 2 + 0) * ZT + z) * HW2;
  float fy = mv[hw];
  float fx = mv[(size_t)ZT * HW2 + hw];
  float gy = fminf(fmaxf((float)h + fy, 0.f), 319.f);
  float gx = fminf(fmaxf((float)w + fx, 0.f), 319.f);
  int y0, x0, y1, x1; float w00, w01, w10, w11;
  corners(gy, gx, y0, x0, y1, x1, w00, w01, w10, w11);
  const float2* xs = x + (size_t)(p * ZT + z) * HW2;
  float2 v00 = xs[y0 * WG + x0], v01 = xs[y0 * WG + x1];
  float2 v10 = xs[y1 * WG + x0], v11 = xs[y1 * WG + x1];
  float2 o;
  o.x = v00.x * w00 + v01.x * w01 + v10.x * w10 + v11.x * w11;
  o.y = v00.y * w00 + v01.y * w01 + v10.y * w10 + v11.y * w11;
  warped[gid] = o;
  // TV gradient
  float2 xc = xs[hw];
  float tre = 0.f, tim = 0.f;
  if (h > 0){
    float2 n = xs[hw - WG];
    float dr = xc.x - n.x, di = xc.y - n.y;
    float r = sqrtf(dr * dr + di * di + 1e-8f);
    tre += dr / r; tim += di / r;
  }
  if (h < HG - 1){
    float2 n = xs[hw + WG];
    float dr = n.x - xc.x, di = n.y - xc.y;
    float r = sqrtf(dr * dr + di * di + 1e-8f);
    tre -= dr / r; tim -= di / r;
  }
  if (w > 0){
    float2 n = xs[hw - 1];
    float dr = xc.x - n.x, di = xc.y - n.y;
    float r = sqrtf(dr * dr + di * di + 1e-8f);
    tre += dr / r; tim += di / r;
  }
  if (w < WG - 1){
    float2 n = xs[hw + 1];
    float dr = n.x - xc.x, di = n.y - xc.y;
    float r = sqrtf(dr * dr + di * di + 1e-8f);
    tre -= dr / r; tim -= di / r;
  }
  gtv[gid] = make_float2(tre, -tim);
}

// row FFT forward: 8 rows of one slice per block (8 waves); output written TRANSPOSED:
// FT_[sl][w][h] (addr = sl*HW2 + w*HG + h) so the column pass reads contiguously.
__global__ __launch_bounds__(512) void k_fft_row_fwd(const float2* __restrict__ warped, const float2* __restrict__ csm,
                                                     float2* __restrict__ FT_, int p0){
  __shared__ float2 seg[8 * LSTR];
  FT f = ft_init();
  int wid = threadIdx.x >> 6, l = f.lane;
  int hg = blockIdx.x % 40; int sl = blockIdx.x / 40;      // sl = (pp*CHN + c)*ZE + zz
  int zz = sl % ZE; int s2 = sl / ZE; int c = s2 % CHN; int pp = s2 / CHN;
  int p = p0 + pp; int z = zz + 1;
  int h = hg * 8 + wid;
  const float2* wr = warped + ((size_t)(p * ZE + zz)) * HW2 + (size_t)h * WG;
  const float2* cs = csm + ((size_t)(c * ZT + z)) * HW2 + (size_t)h * WG;
  float sgn = ((h + l) & 1) ? -1.f : 1.f;
  float2 a[5];
  #pragma unroll
  for (int q = 0; q < 5; q++){
    float2 v = cmul(wr[64 * q + l], cs[64 * q + l]);
    a[q] = make_float2(v.x * sgn, v.y * sgn);
  }
  fft320w(a, f, seg + wid * LSTR);
  __syncthreads();
  float2* out = FT_ + (size_t)sl * HW2 + hg * 8;           // + w*HG later
  for (int i = threadIdx.x; i < 8 * WG; i += 512){
    int w = i >> 3; int hh = i & 7;
    out[(size_t)w * HG + hh] = seg[hh * LSTR + w];
  }
}

// fused forward: per block, 8 owned F-columns + 1 overlap; all column inputs loaded to
// registers first, FFT'd, spectrum to LDS, then sample k-points with x0 in [cbase, cbase+8).
__global__ __launch_bounds__(256) void k_fft_col_sample(const float2* __restrict__ FT_, const float4* __restrict__ permx,
                                                        const unsigned* __restrict__ xbnd, float2* __restrict__ est,
                                                        unsigned int* __restrict__ dmax, int p0){
  __shared__ float2 seg[9 * LSTR];   // 23,112 B
  FT f = ft_init();
  int tid = threadIdx.x; int wid = tid >> 6, l = f.lane;
  int cg = blockIdx.x % 40; int sl = blockIdx.x / 40;       // local slice (pp*CHN+c)*ZE+zz
  int s2 = sl / ZE; int pp = s2 / CHN;
  int p = p0 + pp;
  int cbase = cg * 8;
  const int ncol = (cbase + 8 <= WG - 1) ? 9 : 8;
  const float2* Fs = FT_ + (size_t)sl * HW2 + (size_t)cbase * HG;
  float2 areg[3][5];
  #pragma unroll
  for (int cc = 0; cc < 3; cc++){
    int col = cc * 4 + wid;
    if (col < ncol){
      const float2* src = Fs + (size_t)col * HG;
      #pragma unroll
      for (int q = 0; q < 5; q++) areg[cc][q] = src[64 * q + l];
    }
  }
  #pragma unroll
  for (int cc = 0; cc < 3; cc++){
    int col = cc * 4 + wid;
    if (col < ncol) fft320w(areg[cc], f, seg + col * LSTR);
  }
  __syncthreads();
  int lo = (int)xbnd[p * (WG + 1) + cbase];
  int hi = (int)xbnd[p * (WG + 1) + min(cbase + 8, WG)];
  float2* eb = est + ((size_t)(p0 * CHN * ZE) + sl) * NKP;
  const float4* px = permx + p * NKP;
  float md2 = 0.f;
  for (int j = lo + tid; j < hi; j += 256){
    float4 e4 = px[j];
    int y0, x0, y1, x1; float w00, w01, w10, w11;
    corners(e4.y, e4.z, y0, x0, y1, x1, w00, w01, w10, w11);
    int lc0 = x0 - cbase, lc1 = x1 - cbase;
    float2 v00 = seg[lc0 * LSTR + y0], v01 = seg[lc1 * LSTR + y0];
    float2 v10 = seg[lc0 * LSTR + y1], v11 = seg[lc1 * LSTR + y1];
    float2 e;
    e.x = v00.x * w00 + v01.x * w01 + v10.x * w10 + v11.x * w11;
    e.y = v00.y * w00 + v01.y * w01 + v10.y * w10 + v11.y * w11;
    eb[j] = e;
    md2 = fmaxf(md2, e.x * e.x + e.y * e.y);
  }
  for (int off = 32; off > 0; off >>= 1) md2 = fmaxf(md2, __shfl_down(md2, off, 64));
  if ((tid & 63) == 0 && md2 > 0.f) atomicMax(dmax, __float_as_uint(md2));
}

// backward: fused { weights (est->G on the fly) + zero tile + x-bucketed corner scatter
// (LDS atomics) + per-wave column DFT^T }. F written in NORMAL layout (row_bwd reads rows).
__global__ __launch_bounds__(256) void k_fft_col_scatter(const float2* __restrict__ est, const float2* __restrict__ kdata,
                                                         const float4* __restrict__ permx,
                                                         const unsigned* __restrict__ xbnd,
                                                         const unsigned int* __restrict__ dmax,
                                                         float2* __restrict__ F, int p0){
  __shared__ float2 ld[16 * LSTR];
  FT f = ft_init();
  int tid = threadIdx.x; int wid = tid >> 6, l = f.lane;
  int cg = blockIdx.x % 20; int sl = blockIdx.x / 20;       // local slice
  int zz = sl % ZE; int s2 = sl / ZE; int c = s2 % CHN; int pp = s2 / CHN;
  int p = p0 + pp; int z = zz + 1;
  for (int i = tid; i < 16 * LSTR; i += 256) ld[i] = make_float2(0.f, 0.f);
  __syncthreads();
  float md = sqrtf(__uint_as_float(*dmax));
  int cbase = cg * 16;
  int lo = (cbase > 0) ? (int)xbnd[p * (WG + 1) + cbase - 1] : 0;
  int hi = (int)xbnd[p * (WG + 1) + min(cbase + 16, WG)];
  const float2* Es = est + ((size_t)(p0 * CHN * ZE) + sl) * NKP;
  const float2* kd = kdata + ((size_t)(p * CHN + c) * ZT + z) * NKP;
  const float4* px = permx + p * NKP;
  for (int j = lo + tid; j < hi; j += 256){
    float4 e4 = px[j];
    int k = (int)__float_as_uint(e4.x);
    int y0, x0, y1, x1; float w00, w01, w10, w11;
    corners(e4.y, e4.z, y0, x0, y1, x1, w00, w01, w10, w11);
    float2 e = Es[j];
    float det = sqrtf(e.x * e.x + e.y * e.y);
    float wv = 1.0f / (det / md + EPS_C);
    float sc = wv * wv * INV_N;
    float2 y = kd[k];
    float2 gv = make_float2(sc * (e.x - y.x), -sc * (e.y - y.y));
    int c0 = x0 - cbase, c1 = x1 - cbase;
    if ((unsigned)c0 < 16u){
      atomicAdd(&ld[c0 * LSTR + y0].x, gv.x * w00); atomicAdd(&ld[c0 * LSTR + y0].y, gv.y * w00);
      atomicAdd(&ld[c0 * LSTR + y1].x, gv.x * w10); atomicAdd(&ld[c0 * LSTR + y1].y, gv.y * w10);
    }
    if ((unsigned)c1 < 16u){
      atomicAdd(&ld[c1 * LSTR + y0].x, gv.x * w01); atomicAdd(&ld[c1 * LSTR + y0].y, gv.y * w01);
      atomicAdd(&ld[c1 * LSTR + y1].x, gv.x * w11); atomicAdd(&ld[c1 * LSTR + y1].y, gv.y * w11);
    }
  }
  __syncthreads();
  #pragma unroll
  for (int cc = 0; cc < 4; cc++){
    float2* base = ld + (wid * 4 + cc) * LSTR;
    float2 a[5];
    #pragma unroll
    for (int q = 0; q < 5; q++) a[q] = base[64 * q + l];
    fft320w(a, f, base);
  }
  __syncthreads();
  float2* Fs = F + (size_t)sl * HW2 + cbase;
  for (int i = tid; i < 5120; i += 256){ int h = i >> 4, col = i & 15; Fs[h * WG + col] = ld[col * LSTR + h]; }
}

// transpose row pass: 8 waves = 8 coils of one (pp,zz,h) row; epilogue *(-1)^(h+w), *csm, coil sum
__global__ __launch_bounds__(512) void k_fft_row_bwd(const float2* __restrict__ F, const float2* __restrict__ csm,
                                                     float2* __restrict__ gwarped, int p0){
  __shared__ float2 seg[8 * LSTR];
  FT f = ft_init();
  int tid = threadIdx.x; int c = tid >> 6, l = f.lane;
  int bid = blockIdx.x;                          // over np*ZE*HG
  int h = bid % HG; int b2 = bid / HG;
  int zz = b2 % ZE; int pp = b2 / ZE;
  int p = p0 + pp; int z = zz + 1;
  const float2* Fl = F + ((size_t)((pp * CHN + c) * ZE + zz)) * HW2 + (size_t)h * WG;
  float2 a[5];
  #pragma unroll
  for (int q = 0; q < 5; q++) a[q] = Fl[64 * q + l];
  fft320w(a, f, seg + c * LSTR);
  __syncthreads();
  if (tid < WG){
    int w = tid;
    float2 acc = make_float2(0.f, 0.f);
    #pragma unroll
    for (int cc = 0; cc < 8; cc++){
      cmac(acc, seg[cc * LSTR + w], csm[((size_t)(cc * ZT + z)) * HW2 + (size_t)h * WG + w]);
    }
    float sg = ((h + w) & 1) ? -1.f : 1.f;
    gwarped[((size_t)(p * ZE + zz)) * HW2 + (size_t)h * WG + w] = make_float2(acc.x * sg, acc.y * sg);
  }
}

// ---------------- gather-tiled warp adjoint + fused gradient update ----------------
#define TRG 8
#define HAG 8
__global__ __launch_bounds__(512) void k_warpadj_update(const float2* __restrict__ gw, const float* __restrict__ mvf,
                                                        const float2* __restrict__ gtv, const float* __restrict__ stdp,
                                                        float2* __restrict__ x,
                                                        uint4* __restrict__ fb, unsigned int* __restrict__ fbcnt){
  __shared__ float lt[TRG * WG * 2];   // 20480 B
  int tid = threadIdx.x;
  int bid = blockIdx.x;                    // pz*40 + tile
  int tile = bid % 40; int pz = bid / 40;
  int zz = pz % ZE, p = pz / ZE, z = zz + 1;
  int R = tile * TRG;
  for (int i = tid; i < TRG * WG * 2; i += 512) lt[i] = 0.f;
  __syncthreads();
  const float* mvy = mvf + ((size_t)(p * 2 + 0) * ZT + z) * HW2;
  const float* mvx = mvy + (size_t)ZT * HW2;
  const float2* g = gw + (size_t)pz * HW2;
  const size_t xbase = (size_t)(p * ZT + z) * HW2;
  int wlo = max(R - HAG, 0), whi = min(R + TRG + HAG, HG);
  int npx = (whi - wlo) * WG;
  int base0 = wlo * WG;
  int i = tid;
  float fy = 0.f, fx = 0.f; float2 gv = make_float2(0.f, 0.f);
  if (i < npx){ fy = mvy[base0 + i]; fx = mvx[base0 + i]; gv = g[base0 + i]; }
  while (i < npx){
    int inx = i + 512;
    float fy2 = 0.f, fx2 = 0.f; float2 gv2 = make_float2(0.f, 0.f);
    if (inx < npx){ fy2 = mvy[base0 + inx]; fx2 = mvx[base0 + inx]; gv2 = g[base0 + inx]; }
    int hh = i / WG; int w = i - hh * WG;
    int h = wlo + hh;
    float gy = fminf(fmaxf((float)h + fy, 0.f), 319.f);
    float gx = fminf(fmaxf((float)w + fx, 0.f), 319.f);
    int y0, x0, y1, x1; float w00, w01, w10, w11;
    corners(gy, gx, y0, x0, y1, x1, w00, w01, w10, w11);
    bool owner = (h >= R) && (h < R + TRG);
    #define PROC(Y, XC, WT) { \
      int ry = (Y) - R; \
      if ((unsigned)ry < (unsigned)TRG){ \
        atomicAdd(&lt[(ry * WG + (XC)) * 2 + 0], gv.x * (WT)); \
        atomicAdd(&lt[(ry * WG + (XC)) * 2 + 1], gv.y * (WT)); \
      } else if (owner){ \
        int Ry = (Y) & ~(TRG - 1); \
        if (h < Ry - HAG || h >= Ry + TRG + HAG){ \
          unsigned slot = atomicAdd(fbcnt, 1u); \
          if (slot < FBCAP) fb[slot] = make_uint4((unsigned)(xbase + (size_t)(Y) * WG + (XC)), \
                                                  __float_as_uint(gv.x * (WT)), __float_as_uint(gv.y * (WT)), 0u); \
        } \
      } \
    }
    PROC(y0, x0, w00); PROC(y0, x1, w01); PROC(y1, x0, w10); PROC(y1, x1, w11);
    #undef PROC
    i = inx; fy = fy2; fx = fx2; gv = gv2;
  }
  __syncthreads();
  float s = stdp[0];
  const float2* gt = gtv + (size_t)pz * HW2;
  for (int i2 = tid; i2 < TRG * WG; i2 += 512){
    int yy = i2 / WG; int w = i2 - yy * WG;
    int hw = (R + yy) * WG + w;
    float2 xv = x[xbase + hw];
    float2 tv = gt[hw];
    xv.x -= GAMMA_C * lt[i2 * 2 + 0] + TAU_C * s * tv.x;
    xv.y -= GAMMA_C * lt[i2 * 2 + 1] + TAU_C * s * tv.y;
    x[xbase + hw] = xv;
  }
}

// apply rare out-of-halo contributions: x[idx] -= GAMMA * val
__global__ __launch_bounds__(256) void k_fixup(const uint4* __restrict__ fb, const unsigned int* __restrict__ fbcnt,
                                               float2* __restrict__ x){
  unsigned n = *fbcnt; if (n > FBCAP) n = FBCAP;
  for (unsigned i = blockIdx.x * 256 + threadIdx.x; i < n; i += gridDim.x * 256){
    uint4 e = fb[i];
    atomicAdd(&x[e.x].x, -GAMMA_C * __uint_as_float(e.y));
    atomicAdd(&x[e.x].y, -GAMMA_C * __uint_as_float(e.z));
  }
}

// ---------------- host ----------------
extern "C" void kernel_launch(void* const* d_in, const int* in_sizes, int n_in,
                              void* d_out, int out_size, void* d_ws, size_t ws_size,
                              hipStream_t stream) {
  const float2* kdata = (const float2*)d_in[0];
  const float*  traj  = (const float*) d_in[1];
  const float2* img0  = (const float2*)d_in[2];
  const float*  mvf   = (const float*) d_in[3];
  const float2* csm   = (const float2*)d_in[4];
  const float*  stdp  = (const float*) d_in[5];
  float2* x = (float2*)d_out;

  const size_t F_B  = (size_t)CHN * ZE * HW2 * 8;        // 39,321,600
  const size_t W_B  = (size_t)PH * ZE * HW2 * 8;         // 19,660,800
  const size_t E_B  = (size_t)PH * CHN * ZE * NKP * 8;   //  6,291,456
  const size_t FB_B = (size_t)FBCAP * 16;                //  2,097,152
  const size_t P_B  = (size_t)PH * NKP * 16;             //    262,144
  const size_t SORT_B = P_B + 4 * 8192;

  // NP=2: F (2 phases, 78.6 MB) + csm (39 MB) + warped (20 MB) stays L3-resident between
  // producer and consumer dispatches (NP=4's 157 MB F suffered ~50% L3 capacity misses).
  size_t need_big = 2 * F_B + 2 * W_B + E_B + 512 + FB_B + SORT_B;   // ~107 MB
  const int NP = (ws_size >= need_big) ? 2 : 1;

  char* cur = (char*)d_ws;
  float2* F      = (float2*)cur;  cur += (size_t)NP * F_B;   // fwd: transposed; bwd: normal
  float2* warped = (float2*)cur;  cur += W_B;                // also holds gwarped
  float2* est    = (float2*)cur;  cur += E_B;
  float2* gtvb   = (float2*)cur;  cur += W_B;
  unsigned int* dmax  = (unsigned int*)cur; cur += 128;
  unsigned int* fbcnt = (unsigned int*)cur; cur += 128;
  uint4* fb           = (uint4*)cur;        cur += FB_B;
  float4* permx       = (float4*)cur;       cur += P_B;
  unsigned* xhist     = (unsigned*)cur;     cur += 8192;
  unsigned* xcur      = (unsigned*)cur;     cur += 8192;
  unsigned* xbnd      = (unsigned*)cur;     cur += 8192;

  k_init<<<12800, 256, 0, stream>>>(img0, x, PH * ZT * HW2);
  // build x-sorted k-point list (traj constant across iterations)
  hipMemsetAsync(xhist, 0, 8192, stream);
  k_khist<<<64, 256, 0, stream>>>(traj, xhist);
  k_kscan<<<1, 64, 0, stream>>>(xhist, xcur, xbnd);
  k_kperm<<<64, 256, 0, stream>>>(traj, xcur, permx);

  for (int it = 0; it < 3; it++){
    k_warp_tv<<<9600, 256, 0, stream>>>(x, mvf, warped, gtvb, dmax, fbcnt);
    for (int p0 = 0; p0 < PH; p0 += NP){
      k_fft_row_fwd   <<<NP * 1920, 512, 0, stream>>>(warped, csm, F, p0);
      k_fft_col_sample<<<NP * 1920, 256, 0, stream>>>(F, permx, xbnd, est, dmax, p0);
    }
    for (int p0 = 0; p0 < PH; p0 += NP){
      k_fft_col_scatter<<<NP *  960, 256, 0, stream>>>(est, kdata, permx, xbnd, dmax, F, p0);
      k_fft_row_bwd    <<<NP * 1920, 512, 0, stream>>>(F, csm, warped, p0);
    }
    k_warpadj_update<<<960, 512, 0, stream>>>(warped, mvf, gtvb, stdp, x, fb, fbcnt);
    k_fixup<<<16, 256, 0, stream>>>(fb, fbcnt, x);
  }
}

// Round 14
// 1765.828 us; speedup vs baseline: 1.0523x; 1.0523x over previous
//
#include <hip/hip_runtime.h>
#include <math.h>

// ---------------- problem constants ----------------
#define PH   4
#define CHN  8
#define ZT   8
#define ZE   6          // effective z slices: z in [1,7)
#define HG   320
#define WG   320
#define HW2  102400     // 320*320
#define NKP  4096
#define LSTR 321        // LDS line stride (pad +1)
#define FBCAP 131072u   // fallback list capacity (entries)

constexpr float GAMMA_C = 0.1f;
constexpr float TAU_C   = 0.2f;
constexpr float EPS_C   = 0.01f;
constexpr float INV_N   = 1.0f / 786432.0f;   // PH*CHN*ZE*NKP
#define TWO_PI_F 6.28318530717958647692f

// W5^j = e^{-2*pi*i*j/5}
constexpr float W5R[5] = { 1.f,  0.30901699f, -0.80901699f, -0.80901699f,  0.30901699f};
constexpr float W5I[5] = { 0.f, -0.95105652f, -0.58778525f,  0.58778525f,  0.95105652f};

// ---------------- complex helpers ----------------
__device__ __forceinline__ float2 cmul(float2 a, float2 b){
  return make_float2(a.x*b.x - a.y*b.y, a.x*b.y + a.y*b.x);
}
__device__ __forceinline__ void cmac(float2& d, float2 a, float2 b){
  d.x = fmaf(a.x, b.x, fmaf(-a.y, b.y, d.x));
  d.y = fmaf(a.x, b.y, fmaf( a.y, b.x, d.y));
}

// bf16-packed complex: re in low 16, im in high 16 (round-to-nearest-even)
__device__ __forceinline__ unsigned pk(float2 v){
  unsigned ua = __float_as_uint(v.x), ub = __float_as_uint(v.y);
  ua = (ua + 0x7FFFu + ((ua >> 16) & 1u)) >> 16;
  ub = (ub + 0x7FFFu + ((ub >> 16) & 1u)) >> 16;
  return ua | (ub << 16);
}
__device__ __forceinline__ float2 upk(unsigned v){
  return make_float2(__uint_as_float(v << 16), __uint_as_float(v & 0xFFFF0000u));
}

__device__ __forceinline__ void corners(float gy, float gx, int& y0, int& x0, int& y1, int& x1,
                                        float& w00, float& w01, float& w10, float& w11){
  float y0f = floorf(gy), x0f = floorf(gx);
  float wy = gy - y0f, wx = gx - x0f;
  y0 = (int)y0f; x0 = (int)x0f;
  y1 = min(y0 + 1, HG - 1); x1 = min(x0 + 1, WG - 1);
  w00 = (1.f - wy) * (1.f - wx);
  w01 = (1.f - wy) * wx;
  w10 = wy * (1.f - wx);
  w11 = wy * wx;
}

__device__ __forceinline__ void traj_to_grid(float ty, float tx, float& gy, float& gx){
  gy = fminf(fmaxf((ty / TWO_PI_F + 0.5f) * 320.f, 0.f), 319.f);
  gx = fminf(fmaxf((tx / TWO_PI_F + 0.5f) * 320.f, 0.f), 319.f);
}

// ---------------- in-register 320-pt FFT: one wave per line, N = 5 x 64 ----------------
// (verified rounds 5-13). Lane l stores X[5*br6(l)+r]; un-permuted via LDS seg.
struct FT {
  float2 t1, t2, t3, t4;
  float2 tw0, tw1, tw2, tw3, tw4;
  int br5, lane;
};

__device__ __forceinline__ FT ft_init(){
  FT f; int l = (int)(threadIdx.x & 63); f.lane = l;
  sincosf(-TWO_PI_F * (float)l * (1.0f/320.0f), &f.t1.y, &f.t1.x);
  f.t2 = cmul(f.t1, f.t1); f.t3 = cmul(f.t2, f.t1); f.t4 = cmul(f.t2, f.t2);
  sincosf(-TWO_PI_F * (float)(l & 31) * (1.0f/64.0f), &f.tw0.y, &f.tw0.x);
  sincosf(-TWO_PI_F * (float)(l & 15) * (1.0f/32.0f), &f.tw1.y, &f.tw1.x);
  sincosf(-TWO_PI_F * (float)(l &  7) * (1.0f/16.0f), &f.tw2.y, &f.tw2.x);
  sincosf(-TWO_PI_F * (float)(l &  3) * (1.0f/ 8.0f), &f.tw3.y, &f.tw3.x);
  f.tw4 = (l & 1) ? make_float2(0.f, -1.f) : make_float2(1.f, 0.f);
  int br = ((l&1)<<5) | ((l&2)<<3) | ((l&4)<<1) | ((l&8)>>1) | ((l&16)>>3) | ((l&32)>>5);
  f.br5 = 5 * br;
  return f;
}

template<int H>
__device__ __forceinline__ void bfly(float2& v, float2 tw, int lane){
  float px = __shfl_xor(v.x, H, 64);
  float py = __shfl_xor(v.y, H, 64);
  bool up = (lane & H) != 0;
  float ax = up ? px : v.x, ay = up ? py : v.y;
  float bx = up ? v.x : px, by = up ? v.y : py;
  float dx = ax - bx,  dy = ay - by;
  float mx = fmaf(dx, tw.x, -dy * tw.y);
  float my = fmaf(dx, tw.y,  dy * tw.x);
  v.x = up ? mx : (ax + bx);
  v.y = up ? my : (ay + by);
}

__device__ __forceinline__ void fft320w(const float2 a[5], const FT& f, float2* __restrict__ seg){
  float2 z[5];
  #pragma unroll
  for (int r = 0; r < 5; r++){
    float2 acc = a[0];
    #pragma unroll
    for (int q = 1; q < 5; q++){
      const int j = (q * r) % 5;
      cmac(acc, a[q], make_float2(W5R[j], W5I[j]));
    }
    z[r] = acc;
  }
  z[1] = cmul(z[1], f.t1); z[2] = cmul(z[2], f.t2);
  z[3] = cmul(z[3], f.t3); z[4] = cmul(z[4], f.t4);
  #pragma unroll
  for (int r = 0; r < 5; r++){
    float2 v = z[r];
    bfly<32>(v, f.tw0, f.lane);
    bfly<16>(v, f.tw1, f.lane);
    bfly< 8>(v, f.tw2, f.lane);
    bfly< 4>(v, f.tw3, f.lane);
    bfly< 2>(v, f.tw4, f.lane);
    {
      float px = __shfl_xor(v.x, 1, 64);
      float py = __shfl_xor(v.y, 1, 64);
      bool up = (f.lane & 1) != 0;
      float ax = up ? px : v.x, ay = up ? py : v.y;
      float bx = up ? v.x : px, by = up ? v.y : py;
      v.x = up ? (ax - bx) : (ax + bx);
      v.y = up ? (ay - by) : (ay + by);
    }
    seg[f.br5 + r] = v;
  }
}

// ---------------- k-point x-sorting (once per call; traj constant across iterations) --------
__global__ __launch_bounds__(256) void k_khist(const float* __restrict__ traj, unsigned* __restrict__ xhist){
  int gid = blockIdx.x * 256 + threadIdx.x;
  if (gid >= PH * NKP) return;
  int p = gid >> 12, k = gid & (NKP - 1);
  float gy, gx;
  traj_to_grid(traj[(p * 2 + 0) * NKP + k], traj[(p * 2 + 1) * NKP + k], gy, gx);
  atomicAdd(&xhist[p * WG + (int)floorf(gx)], 1u);
}

__global__ void k_kscan(const unsigned* __restrict__ xhist, unsigned* __restrict__ xcur,
                        unsigned* __restrict__ xbnd){
  int p = threadIdx.x;
  if (p < PH){
    unsigned acc = 0;
    for (int b = 0; b < WG; b++){ xcur[p * WG + b] = acc; xbnd[p * (WG + 1) + b] = acc; acc += xhist[p * WG + b]; }
    xbnd[p * (WG + 1) + WG] = acc;
  }
}

__global__ __launch_bounds__(256) void k_kperm(const float* __restrict__ traj, unsigned* __restrict__ xcur,
                                               float4* __restrict__ permx){
  int gid = blockIdx.x * 256 + threadIdx.x;
  if (gid >= PH * NKP) return;
  int p = gid >> 12, k = gid & (NKP - 1);
  float gy, gx;
  traj_to_grid(traj[(p * 2 + 0) * NKP + k], traj[(p * 2 + 1) * NKP + k], gy, gx);
  unsigned sx = atomicAdd(&xcur[p * WG + (int)floorf(gx)], 1u);
  permx[p * NKP + sx] = make_float4(__uint_as_float((unsigned)k), gy, gx, 0.f);
}

// ---------------- kernels ----------------
__global__ __launch_bounds__(256) void k_init(const float2* __restrict__ img0, float2* __restrict__ x, int n){
  int i = blockIdx.x * 256 + threadIdx.x;
  if (i < n){
    float2 v = img0[i];
    v.x = isnan(v.x) ? 0.f : fminf(fmaxf(v.x, -3.4028235e38f), 3.4028235e38f);
    v.y = isnan(v.y) ? 0.f : fminf(fmaxf(v.y, -3.4028235e38f), 3.4028235e38f);
    x[i] = v;
  }
}

// fused: warped = bilinear-warp(x, mvf); gtv = conj(TV-grad(x)); also zeroes dmax/fbcnt
__global__ __launch_bounds__(256) void k_warp_tv(const float2* __restrict__ x, const float* __restrict__ mvf,
                                                 float2* __restrict__ warped, float2* __restrict__ gtv,
                                                 unsigned int* __restrict__ dmax, unsigned int* __restrict__ fbcnt){
  if (blockIdx.x == 0 && threadIdx.x == 0){ *dmax = 0u; *fbcnt = 0u; }
  int gid = blockIdx.x * 256 + threadIdx.x;          // over PH*ZE*HW2
  int hw = gid % HW2;
  int pz = gid / HW2;
  int zz = pz % ZE, p = pz / ZE, z = zz + 1;
  int h = hw / WG, w = hw - h * WG;
  const float* mv = mvf + ((size_t)(p * 2 + 0) * ZT + z) * HW2;
  float fy = mv[hw];
  float fx = mv[(size_t)ZT * HW2 + hw];
  float gy = fminf(fmaxf((float)h + fy, 0.f), 319.f);
  float gx = fminf(fmaxf((float)w + fx, 0.f), 319.f);
  int y0, x0, y1, x1; float w00, w01, w10, w11;
  corners(gy, gx, y0, x0, y1, x1, w00, w01, w10, w11);
  const float2* xs = x + (size_t)(p * ZT + z) * HW2;
  float2 v00 = xs[y0 * WG + x0], v01 = xs[y0 * WG + x1];
  float2 v10 = xs[y1 * WG + x0], v11 = xs[y1 * WG + x1];
  float2 o;
  o.x = v00.x * w00 + v01.x * w01 + v10.x * w10 + v11.x * w11;
  o.y = v00.y * w00 + v01.y * w01 + v10.y * w10 + v11.y * w11;
  warped[gid] = o;
  // TV gradient
  float2 xc = xs[hw];
  float tre = 0.f, tim = 0.f;
  if (h > 0){
    float2 n = xs[hw - WG];
    float dr = xc.x - n.x, di = xc.y - n.y;
    float r = sqrtf(dr * dr + di * di + 1e-8f);
    tre += dr / r; tim += di / r;
  }
  if (h < HG - 1){
    float2 n = xs[hw + WG];
    float dr = n.x - xc.x, di = n.y - xc.y;
    float r = sqrtf(dr * dr + di * di + 1e-8f);
    tre -= dr / r; tim -= di / r;
  }
  if (w > 0){
    float2 n = xs[hw - 1];
    float dr = xc.x - n.x, di = xc.y - n.y;
    float r = sqrtf(dr * dr + di * di + 1e-8f);
    tre += dr / r; tim += di / r;
  }
  if (w < WG - 1){
    float2 n = xs[hw + 1];
    float dr = n.x - xc.x, di = n.y - xc.y;
    float r = sqrtf(dr * dr + di * di + 1e-8f);
    tre -= dr / r; tim -= di / r;
  }
  gtv[gid] = make_float2(tre, -tim);
}

// row FFT forward: 8 rows of one slice per block (8 waves); output TRANSPOSED + bf16-packed:
// FT_[sl][w][h] (addr = sl*HW2 + w*HG + h), 4 B per complex.
__global__ __launch_bounds__(512) void k_fft_row_fwd(const float2* __restrict__ warped, const float2* __restrict__ csm,
                                                     unsigned* __restrict__ FT_, int p0){
  __shared__ float2 seg[8 * LSTR];
  FT f = ft_init();
  int wid = threadIdx.x >> 6, l = f.lane;
  int hg = blockIdx.x % 40; int sl = blockIdx.x / 40;      // sl = (pp*CHN + c)*ZE + zz
  int zz = sl % ZE; int s2 = sl / ZE; int c = s2 % CHN; int pp = s2 / CHN;
  int p = p0 + pp; int z = zz + 1;
  int h = hg * 8 + wid;
  const float2* wr = warped + ((size_t)(p * ZE + zz)) * HW2 + (size_t)h * WG;
  const float2* cs = csm + ((size_t)(c * ZT + z)) * HW2 + (size_t)h * WG;
  float sgn = ((h + l) & 1) ? -1.f : 1.f;
  float2 a[5];
  #pragma unroll
  for (int q = 0; q < 5; q++){
    float2 v = cmul(wr[64 * q + l], cs[64 * q + l]);
    a[q] = make_float2(v.x * sgn, v.y * sgn);
  }
  fft320w(a, f, seg + wid * LSTR);
  __syncthreads();
  unsigned* out = FT_ + (size_t)sl * HW2 + hg * 8;         // + w*HG later
  for (int i = threadIdx.x; i < 8 * WG; i += 512){
    int w = i >> 3; int hh = i & 7;
    out[(size_t)w * HG + hh] = pk(seg[hh * LSTR + w]);
  }
}

// fused forward: per block, 8 owned F-columns + 1 overlap; bf16 columns loaded to registers,
// unpacked, FFT'd, spectrum to LDS, then sample k-points with x0 in [cbase, cbase+8).
__global__ __launch_bounds__(256) void k_fft_col_sample(const unsigned* __restrict__ FT_, const float4* __restrict__ permx,
                                                        const unsigned* __restrict__ xbnd, float2* __restrict__ est,
                                                        unsigned int* __restrict__ dmax, int p0){
  __shared__ float2 seg[9 * LSTR];   // 23,112 B
  FT f = ft_init();
  int tid = threadIdx.x; int wid = tid >> 6, l = f.lane;
  int cg = blockIdx.x % 40; int sl = blockIdx.x / 40;       // local slice (pp*CHN+c)*ZE+zz
  int s2 = sl / ZE; int pp = s2 / CHN;
  int p = p0 + pp;
  int cbase = cg * 8;
  const int ncol = (cbase + 8 <= WG - 1) ? 9 : 8;
  const unsigned* Fs = FT_ + (size_t)sl * HW2 + (size_t)cbase * HG;
  unsigned raw[3][5];
  #pragma unroll
  for (int cc = 0; cc < 3; cc++){
    int col = cc * 4 + wid;
    if (col < ncol){
      const unsigned* src = Fs + (size_t)col * HG;
      #pragma unroll
      for (int q = 0; q < 5; q++) raw[cc][q] = src[64 * q + l];
    }
  }
  #pragma unroll
  for (int cc = 0; cc < 3; cc++){
    int col = cc * 4 + wid;
    if (col < ncol){
      float2 a[5];
      #pragma unroll
      for (int q = 0; q < 5; q++) a[q] = upk(raw[cc][q]);
      fft320w(a, f, seg + col * LSTR);
    }
  }
  __syncthreads();
  int lo = (int)xbnd[p * (WG + 1) + cbase];
  int hi = (int)xbnd[p * (WG + 1) + min(cbase + 8, WG)];
  float2* eb = est + ((size_t)(p0 * CHN * ZE) + sl) * NKP;
  const float4* px = permx + p * NKP;
  float md2 = 0.f;
  for (int j = lo + tid; j < hi; j += 256){
    float4 e4 = px[j];
    int y0, x0, y1, x1; float w00, w01, w10, w11;
    corners(e4.y, e4.z, y0, x0, y1, x1, w00, w01, w10, w11);
    int lc0 = x0 - cbase, lc1 = x1 - cbase;
    float2 v00 = seg[lc0 * LSTR + y0], v01 = seg[lc1 * LSTR + y0];
    float2 v10 = seg[lc0 * LSTR + y1], v11 = seg[lc1 * LSTR + y1];
    float2 e;
    e.x = v00.x * w00 + v01.x * w01 + v10.x * w10 + v11.x * w11;
    e.y = v00.y * w00 + v01.y * w01 + v10.y * w10 + v11.y * w11;
    eb[j] = e;
    md2 = fmaxf(md2, e.x * e.x + e.y * e.y);
  }
  for (int off = 32; off > 0; off >>= 1) md2 = fmaxf(md2, __shfl_down(md2, off, 64));
  if ((tid & 63) == 0 && md2 > 0.f) atomicMax(dmax, __float_as_uint(md2));
}

// backward: fused { weights (est->G on the fly) + zero tile + x-bucketed corner scatter
// (LDS atomics) + per-wave column DFT^T }. F written NORMAL layout, bf16-packed.
__global__ __launch_bounds__(256) void k_fft_col_scatter(const float2* __restrict__ est, const float2* __restrict__ kdata,
                                                         const float4* __restrict__ permx,
                                                         const unsigned* __restrict__ xbnd,
                                                         const unsigned int* __restrict__ dmax,
                                                         unsigned* __restrict__ F, int p0){
  __shared__ float2 ld[16 * LSTR];
  FT f = ft_init();
  int tid = threadIdx.x; int wid = tid >> 6, l = f.lane;
  int cg = blockIdx.x % 20; int sl = blockIdx.x / 20;       // local slice
  int zz = sl % ZE; int s2 = sl / ZE; int c = s2 % CHN; int pp = s2 / CHN;
  int p = p0 + pp; int z = zz + 1;
  for (int i = tid; i < 16 * LSTR; i += 256) ld[i] = make_float2(0.f, 0.f);
  __syncthreads();
  float md = sqrtf(__uint_as_float(*dmax));
  int cbase = cg * 16;
  int lo = (cbase > 0) ? (int)xbnd[p * (WG + 1) + cbase - 1] : 0;
  int hi = (int)xbnd[p * (WG + 1) + min(cbase + 16, WG)];
  const float2* Es = est + ((size_t)(p0 * CHN * ZE) + sl) * NKP;
  const float2* kd = kdata + ((size_t)(p * CHN + c) * ZT + z) * NKP;
  const float4* px = permx + p * NKP;
  for (int j = lo + tid; j < hi; j += 256){
    float4 e4 = px[j];
    int k = (int)__float_as_uint(e4.x);
    int y0, x0, y1, x1; float w00, w01, w10, w11;
    corners(e4.y, e4.z, y0, x0, y1, x1, w00, w01, w10, w11);
    float2 e = Es[j];
    float det = sqrtf(e.x * e.x + e.y * e.y);
    float wv = 1.0f / (det / md + EPS_C);
    float sc = wv * wv * INV_N;
    float2 y = kd[k];
    float2 gv = make_float2(sc * (e.x - y.x), -sc * (e.y - y.y));
    int c0 = x0 - cbase, c1 = x1 - cbase;
    if ((unsigned)c0 < 16u){
      atomicAdd(&ld[c0 * LSTR + y0].x, gv.x * w00); atomicAdd(&ld[c0 * LSTR + y0].y, gv.y * w00);
      atomicAdd(&ld[c0 * LSTR + y1].x, gv.x * w10); atomicAdd(&ld[c0 * LSTR + y1].y, gv.y * w10);
    }
    if ((unsigned)c1 < 16u){
      atomicAdd(&ld[c1 * LSTR + y0].x, gv.x * w01); atomicAdd(&ld[c1 * LSTR + y0].y, gv.y * w01);
      atomicAdd(&ld[c1 * LSTR + y1].x, gv.x * w11); atomicAdd(&ld[c1 * LSTR + y1].y, gv.y * w11);
    }
  }
  __syncthreads();
  #pragma unroll
  for (int cc = 0; cc < 4; cc++){
    float2* base = ld + (wid * 4 + cc) * LSTR;
    float2 a[5];
    #pragma unroll
    for (int q = 0; q < 5; q++) a[q] = base[64 * q + l];
    fft320w(a, f, base);
  }
  __syncthreads();
  unsigned* Fs = F + (size_t)sl * HW2 + cbase;
  for (int i = tid; i < 5120; i += 256){ int h = i >> 4, col = i & 15; Fs[h * WG + col] = pk(ld[col * LSTR + h]); }
}

// transpose row pass: 8 waves = 8 coils of one (pp,zz,h) row; epilogue *(-1)^(h+w), *csm, coil sum
__global__ __launch_bounds__(512) void k_fft_row_bwd(const unsigned* __restrict__ F, const float2* __restrict__ csm,
                                                     float2* __restrict__ gwarped, int p0){
  __shared__ float2 seg[8 * LSTR];
  FT f = ft_init();
  int tid = threadIdx.x; int c = tid >> 6, l = f.lane;
  int bid = blockIdx.x;                          // over np*ZE*HG
  int h = bid % HG; int b2 = bid / HG;
  int zz = b2 % ZE; int pp = b2 / ZE;
  int p = p0 + pp; int z = zz + 1;
  const unsigned* Fl = F + ((size_t)((pp * CHN + c) * ZE + zz)) * HW2 + (size_t)h * WG;
  float2 a[5];
  #pragma unroll
  for (int q = 0; q < 5; q++) a[q] = upk(Fl[64 * q + l]);
  fft320w(a, f, seg + c * LSTR);
  __syncthreads();
  if (tid < WG){
    int w = tid;
    float2 acc = make_float2(0.f, 0.f);
    #pragma unroll
    for (int cc = 0; cc < 8; cc++){
      cmac(acc, seg[cc * LSTR + w], csm[((size_t)(cc * ZT + z)) * HW2 + (size_t)h * WG + w]);
    }
    float sg = ((h + w) & 1) ? -1.f : 1.f;
    gwarped[((size_t)(p * ZE + zz)) * HW2 + (size_t)h * WG + w] = make_float2(acc.x * sg, acc.y * sg);
  }
}

// ---------------- gather-tiled warp adjoint + fused gradient update ----------------
#define TRG 8
#define HAG 8
__global__ __launch_bounds__(512) void k_warpadj_update(const float2* __restrict__ gw, const float* __restrict__ mvf,
                                                        const float2* __restrict__ gtv, const float* __restrict__ stdp,
                                                        float2* __restrict__ x,
                                                        uint4* __restrict__ fb, unsigned int* __restrict__ fbcnt){
  __shared__ float lt[TRG * WG * 2];   // 20480 B
  int tid = threadIdx.x;
  int bid = blockIdx.x;                    // pz*40 + tile
  int tile = bid % 40; int pz = bid / 40;
  int zz = pz % ZE, p = pz / ZE, z = zz + 1;
  int R = tile * TRG;
  for (int i = tid; i < TRG * WG * 2; i += 512) lt[i] = 0.f;
  __syncthreads();
  const float* mvy = mvf + ((size_t)(p * 2 + 0) * ZT + z) * HW2;
  const float* mvx = mvy + (size_t)ZT * HW2;
  const float2* g = gw + (size_t)pz * HW2;
  const size_t xbase = (size_t)(p * ZT + z) * HW2;
  int wlo = max(R - HAG, 0), whi = min(R + TRG + HAG, HG);
  int npx = (whi - wlo) * WG;
  int base0 = wlo * WG;
  int i = tid;
  float fy = 0.f, fx = 0.f; float2 gv = make_float2(0.f, 0.f);
  if (i < npx){ fy = mvy[base0 + i]; fx = mvx[base0 + i]; gv = g[base0 + i]; }
  while (i < npx){
    int inx = i + 512;
    float fy2 = 0.f, fx2 = 0.f; float2 gv2 = make_float2(0.f, 0.f);
    if (inx < npx){ fy2 = mvy[base0 + inx]; fx2 = mvx[base0 + inx]; gv2 = g[base0 + inx]; }
    int hh = i / WG; int w = i - hh * WG;
    int h = wlo + hh;
    float gy = fminf(fmaxf((float)h + fy, 0.f), 319.f);
    float gx = fminf(fmaxf((float)w + fx, 0.f), 319.f);
    int y0, x0, y1, x1; float w00, w01, w10, w11;
    corners(gy, gx, y0, x0, y1, x1, w00, w01, w10, w11);
    bool owner = (h >= R) && (h < R + TRG);
    #define PROC(Y, XC, WT) { \
      int ry = (Y) - R; \
      if ((unsigned)ry < (unsigned)TRG){ \
        atomicAdd(&lt[(ry * WG + (XC)) * 2 + 0], gv.x * (WT)); \
        atomicAdd(&lt[(ry * WG + (XC)) * 2 + 1], gv.y * (WT)); \
      } else if (owner){ \
        int Ry = (Y) & ~(TRG - 1); \
        if (h < Ry - HAG || h >= Ry + TRG + HAG){ \
          unsigned slot = atomicAdd(fbcnt, 1u); \
          if (slot < FBCAP) fb[slot] = make_uint4((unsigned)(xbase + (size_t)(Y) * WG + (XC)), \
                                                  __float_as_uint(gv.x * (WT)), __float_as_uint(gv.y * (WT)), 0u); \
        } \
      } \
    }
    PROC(y0, x0, w00); PROC(y0, x1, w01); PROC(y1, x0, w10); PROC(y1, x1, w11);
    #undef PROC
    i = inx; fy = fy2; fx = fx2; gv = gv2;
  }
  __syncthreads();
  float s = stdp[0];
  const float2* gt = gtv + (size_t)pz * HW2;
  for (int i2 = tid; i2 < TRG * WG; i2 += 512){
    int yy = i2 / WG; int w = i2 - yy * WG;
    int hw = (R + yy) * WG + w;
    float2 xv = x[xbase + hw];
    float2 tv = gt[hw];
    xv.x -= GAMMA_C * lt[i2 * 2 + 0] + TAU_C * s * tv.x;
    xv.y -= GAMMA_C * lt[i2 * 2 + 1] + TAU_C * s * tv.y;
    x[xbase + hw] = xv;
  }
}

// apply rare out-of-halo contributions: x[idx] -= GAMMA * val
__global__ __launch_bounds__(256) void k_fixup(const uint4* __restrict__ fb, const unsigned int* __restrict__ fbcnt,
                                               float2* __restrict__ x){
  unsigned n = *fbcnt; if (n > FBCAP) n = FBCAP;
  for (unsigned i = blockIdx.x * 256 + threadIdx.x; i < n; i += gridDim.x * 256){
    uint4 e = fb[i];
    atomicAdd(&x[e.x].x, -GAMMA_C * __uint_as_float(e.y));
    atomicAdd(&x[e.x].y, -GAMMA_C * __uint_as_float(e.z));
  }
}

// ---------------- host ----------------
extern "C" void kernel_launch(void* const* d_in, const int* in_sizes, int n_in,
                              void* d_out, int out_size, void* d_ws, size_t ws_size,
                              hipStream_t stream) {
  const float2* kdata = (const float2*)d_in[0];
  const float*  traj  = (const float*) d_in[1];
  const float2* img0  = (const float2*)d_in[2];
  const float*  mvf   = (const float*) d_in[3];
  const float2* csm   = (const float2*)d_in[4];
  const float*  stdp  = (const float*) d_in[5];
  float2* x = (float2*)d_out;

  const size_t F_B  = (size_t)CHN * ZE * HW2 * 4;        // 19,660,800 (bf16-packed complex)
  const size_t W_B  = (size_t)PH * ZE * HW2 * 8;         // 19,660,800
  const size_t E_B  = (size_t)PH * CHN * ZE * NKP * 8;   //  6,291,456
  const size_t FB_B = (size_t)FBCAP * 16;                //  2,097,152
  const size_t P_B  = (size_t)PH * NKP * 16;             //    262,144
  const size_t SORT_B = P_B + 4 * 8192;

  size_t need_big = 4 * F_B + 2 * W_B + E_B + 512 + FB_B + SORT_B;   // ~128 MB
  const int NP = (ws_size >= need_big) ? 4 : 1;

  char* cur = (char*)d_ws;
  unsigned* F    = (unsigned*)cur;  cur += (size_t)NP * F_B;  // fwd: transposed; bwd: normal (bf16 packed)
  float2* warped = (float2*)cur;  cur += W_B;                 // also holds gwarped
  float2* est    = (float2*)cur;  cur += E_B;
  float2* gtvb   = (float2*)cur;  cur += W_B;
  unsigned int* dmax  = (unsigned int*)cur; cur += 128;
  unsigned int* fbcnt = (unsigned int*)cur; cur += 128;
  uint4* fb           = (uint4*)cur;        cur += FB_B;
  float4* permx       = (float4*)cur;       cur += P_B;
  unsigned* xhist     = (unsigned*)cur;     cur += 8192;
  unsigned* xcur      = (unsigned*)cur;     cur += 8192;
  unsigned* xbnd      = (unsigned*)cur;     cur += 8192;

  k_init<<<12800, 256, 0, stream>>>(img0, x, PH * ZT * HW2);
  // build x-sorted k-point list (traj constant across iterations)
  hipMemsetAsync(xhist, 0, 8192, stream);
  k_khist<<<64, 256, 0, stream>>>(traj, xhist);
  k_kscan<<<1, 64, 0, stream>>>(xhist, xcur, xbnd);
  k_kperm<<<64, 256, 0, stream>>>(traj, xcur, permx);

  for (int it = 0; it < 3; it++){
    k_warp_tv<<<9600, 256, 0, stream>>>(x, mvf, warped, gtvb, dmax, fbcnt);
    for (int p0 = 0; p0 < PH; p0 += NP){
      k_fft_row_fwd   <<<NP * 1920, 512, 0, stream>>>(warped, csm, F, p0);
      k_fft_col_sample<<<NP * 1920, 256, 0, stream>>>(F, permx, xbnd, est, dmax, p0);
    }
    for (int p0 = 0; p0 < PH; p0 += NP){
      k_fft_col_scatter<<<NP *  960, 256, 0, stream>>>(est, kdata, permx, xbnd, dmax, F, p0);
      k_fft_row_bwd    <<<NP * 1920, 512, 0, stream>>>(F, csm, warped, p0);
    }
    k_warpadj_update<<<960, 512, 0, stream>>>(warped, mvf, gtvb, stdp, x, fb, fbcnt);
    k_fixup<<<16, 256, 0, stream>>>(fb, fbcnt, x);
  }
}

// Round 15
// 1547.468 us; speedup vs baseline: 1.2008x; 1.1411x over previous
//
#include <hip/hip_runtime.h>
#include <math.h>

// ---------------- problem constants ----------------
#define PH   4
#define CHN  8
#define ZT   8
#define ZE   6          // effective z slices: z in [1,7)
#define HG   320
#define WG   320
#define HW2  102400     // 320*320
#define NKP  4096
#define LSTR 321        // LDS line stride (pad +1)
#define FBCAP 131072u   // fallback list capacity (entries)

constexpr float GAMMA_C = 0.1f;
constexpr float TAU_C   = 0.2f;
constexpr float EPS_C   = 0.01f;
constexpr float INV_N   = 1.0f / 786432.0f;   // PH*CHN*ZE*NKP
#define TWO_PI_F 6.28318530717958647692f

// W5^j = e^{-2*pi*i*j/5}
constexpr float W5R[5] = { 1.f,  0.30901699f, -0.80901699f, -0.80901699f,  0.30901699f};
constexpr float W5I[5] = { 0.f, -0.95105652f, -0.58778525f,  0.58778525f,  0.95105652f};

// ---------------- complex helpers ----------------
__device__ __forceinline__ float2 cmul(float2 a, float2 b){
  return make_float2(a.x*b.x - a.y*b.y, a.x*b.y + a.y*b.x);
}
__device__ __forceinline__ void cmac(float2& d, float2 a, float2 b){
  d.x = fmaf(a.x, b.x, fmaf(-a.y, b.y, d.x));
  d.y = fmaf(a.x, b.y, fmaf( a.y, b.x, d.y));
}

// bf16-packed complex: re in low 16, im in high 16 (round-to-nearest-even)
__device__ __forceinline__ unsigned pk(float2 v){
  unsigned ua = __float_as_uint(v.x), ub = __float_as_uint(v.y);
  ua = (ua + 0x7FFFu + ((ua >> 16) & 1u)) >> 16;
  ub = (ub + 0x7FFFu + ((ub >> 16) & 1u)) >> 16;
  return ua | (ub << 16);
}
__device__ __forceinline__ float2 upk(unsigned v){
  return make_float2(__uint_as_float(v << 16), __uint_as_float(v & 0xFFFF0000u));
}

__device__ __forceinline__ void corners(float gy, float gx, int& y0, int& x0, int& y1, int& x1,
                                        float& w00, float& w01, float& w10, float& w11){
  float y0f = floorf(gy), x0f = floorf(gx);
  float wy = gy - y0f, wx = gx - x0f;
  y0 = (int)y0f; x0 = (int)x0f;
  y1 = min(y0 + 1, HG - 1); x1 = min(x0 + 1, WG - 1);
  w00 = (1.f - wy) * (1.f - wx);
  w01 = (1.f - wy) * wx;
  w10 = wy * (1.f - wx);
  w11 = wy * wx;
}

__device__ __forceinline__ void traj_to_grid(float ty, float tx, float& gy, float& gx){
  gy = fminf(fmaxf((ty / TWO_PI_F + 0.5f) * 320.f, 0.f), 319.f);
  gx = fminf(fmaxf((tx / TWO_PI_F + 0.5f) * 320.f, 0.f), 319.f);
}

// ---------------- in-register 320-pt FFT: one wave per line, N = 5 x 64 ----------------
// (verified rounds 5-14). Lane l stores X[5*br6(l)+r]; un-permuted via LDS seg.
struct FT {
  float2 t1, t2, t3, t4;
  float2 tw0, tw1, tw2, tw3, tw4;
  int br5, lane;
};

__device__ __forceinline__ FT ft_init(){
  FT f; int l = (int)(threadIdx.x & 63); f.lane = l;
  sincosf(-TWO_PI_F * (float)l * (1.0f/320.0f), &f.t1.y, &f.t1.x);
  f.t2 = cmul(f.t1, f.t1); f.t3 = cmul(f.t2, f.t1); f.t4 = cmul(f.t2, f.t2);
  sincosf(-TWO_PI_F * (float)(l & 31) * (1.0f/64.0f), &f.tw0.y, &f.tw0.x);
  sincosf(-TWO_PI_F * (float)(l & 15) * (1.0f/32.0f), &f.tw1.y, &f.tw1.x);
  sincosf(-TWO_PI_F * (float)(l &  7) * (1.0f/16.0f), &f.tw2.y, &f.tw2.x);
  sincosf(-TWO_PI_F * (float)(l &  3) * (1.0f/ 8.0f), &f.tw3.y, &f.tw3.x);
  f.tw4 = (l & 1) ? make_float2(0.f, -1.f) : make_float2(1.f, 0.f);
  int br = ((l&1)<<5) | ((l&2)<<3) | ((l&4)<<1) | ((l&8)>>1) | ((l&16)>>3) | ((l&32)>>5);
  f.br5 = 5 * br;
  return f;
}

template<int H>
__device__ __forceinline__ void bfly(float2& v, float2 tw, int lane){
  float px = __shfl_xor(v.x, H, 64);
  float py = __shfl_xor(v.y, H, 64);
  bool up = (lane & H) != 0;
  float ax = up ? px : v.x, ay = up ? py : v.y;
  float bx = up ? v.x : px, by = up ? v.y : py;
  float dx = ax - bx,  dy = ay - by;
  float mx = fmaf(dx, tw.x, -dy * tw.y);
  float my = fmaf(dx, tw.y,  dy * tw.x);
  v.x = up ? mx : (ax + bx);
  v.y = up ? my : (ay + by);
}

__device__ __forceinline__ void fft320w(const float2 a[5], const FT& f, float2* __restrict__ seg){
  float2 z[5];
  #pragma unroll
  for (int r = 0; r < 5; r++){
    float2 acc = a[0];
    #pragma unroll
    for (int q = 1; q < 5; q++){
      const int j = (q * r) % 5;
      cmac(acc, a[q], make_float2(W5R[j], W5I[j]));
    }
    z[r] = acc;
  }
  z[1] = cmul(z[1], f.t1); z[2] = cmul(z[2], f.t2);
  z[3] = cmul(z[3], f.t3); z[4] = cmul(z[4], f.t4);
  #pragma unroll
  for (int r = 0; r < 5; r++){
    float2 v = z[r];
    bfly<32>(v, f.tw0, f.lane);
    bfly<16>(v, f.tw1, f.lane);
    bfly< 8>(v, f.tw2, f.lane);
    bfly< 4>(v, f.tw3, f.lane);
    bfly< 2>(v, f.tw4, f.lane);
    {
      float px = __shfl_xor(v.x, 1, 64);
      float py = __shfl_xor(v.y, 1, 64);
      bool up = (f.lane & 1) != 0;
      float ax = up ? px : v.x, ay = up ? py : v.y;
      float bx = up ? v.x : px, by = up ? v.y : py;
      v.x = up ? (ax - bx) : (ax + bx);
      v.y = up ? (ay - by) : (ay + by);
    }
    seg[f.br5 + r] = v;
  }
}

// ---------------- k-point x-sorting (once per call; traj constant across iterations) --------
__global__ __launch_bounds__(256) void k_khist(const float* __restrict__ traj, unsigned* __restrict__ xhist){
  int gid = blockIdx.x * 256 + threadIdx.x;
  if (gid >= PH * NKP) return;
  int p = gid >> 12, k = gid & (NKP - 1);
  float gy, gx;
  traj_to_grid(traj[(p * 2 + 0) * NKP + k], traj[(p * 2 + 1) * NKP + k], gy, gx);
  atomicAdd(&xhist[p * WG + (int)floorf(gx)], 1u);
}

__global__ void k_kscan(const unsigned* __restrict__ xhist, unsigned* __restrict__ xcur,
                        unsigned* __restrict__ xbnd){
  int p = threadIdx.x;
  if (p < PH){
    unsigned acc = 0;
    for (int b = 0; b < WG; b++){ xcur[p * WG + b] = acc; xbnd[p * (WG + 1) + b] = acc; acc += xhist[p * WG + b]; }
    xbnd[p * (WG + 1) + WG] = acc;
  }
}

__global__ __launch_bounds__(256) void k_kperm(const float* __restrict__ traj, unsigned* __restrict__ xcur,
                                               float4* __restrict__ permx){
  int gid = blockIdx.x * 256 + threadIdx.x;
  if (gid >= PH * NKP) return;
  int p = gid >> 12, k = gid & (NKP - 1);
  float gy, gx;
  traj_to_grid(traj[(p * 2 + 0) * NKP + k], traj[(p * 2 + 1) * NKP + k], gy, gx);
  unsigned sx = atomicAdd(&xcur[p * WG + (int)floorf(gx)], 1u);
  permx[p * NKP + sx] = make_float4(__uint_as_float((unsigned)k), gy, gx, 0.f);
}

// ---------------- kernels ----------------
__global__ __launch_bounds__(256) void k_init(const float2* __restrict__ img0, float2* __restrict__ x, int n){
  int i = blockIdx.x * 256 + threadIdx.x;
  if (i < n){
    float2 v = img0[i];
    v.x = isnan(v.x) ? 0.f : fminf(fmaxf(v.x, -3.4028235e38f), 3.4028235e38f);
    v.y = isnan(v.y) ? 0.f : fminf(fmaxf(v.y, -3.4028235e38f), 3.4028235e38f);
    x[i] = v;
  }
}

// fused: warped = bilinear-warp(x, mvf); gtv = conj(TV-grad(x)); also zeroes dmax/fbcnt
__global__ __launch_bounds__(256) void k_warp_tv(const float2* __restrict__ x, const float* __restrict__ mvf,
                                                 float2* __restrict__ warped, float2* __restrict__ gtv,
                                                 unsigned int* __restrict__ dmax, unsigned int* __restrict__ fbcnt){
  if (blockIdx.x == 0 && threadIdx.x == 0){ *dmax = 0u; *fbcnt = 0u; }
  int gid = blockIdx.x * 256 + threadIdx.x;          // over PH*ZE*HW2
  int hw = gid % HW2;
  int pz = gid / HW2;
  int zz = pz % ZE, p = pz / ZE, z = zz + 1;
  int h = hw / WG, w = hw - h * WG;
  const float* mv = mvf + ((size_t)(p * 2 + 0) * ZT + z) * HW2;
  float fy = mv[hw];
  float fx = mv[(size_t)ZT * HW2 + hw];
  float gy = fminf(fmaxf((float)h + fy, 0.f), 319.f);
  float gx = fminf(fmaxf((float)w + fx, 0.f), 319.f);
  int y0, x0, y1, x1; float w00, w01, w10, w11;
  corners(gy, gx, y0, x0, y1, x1, w00, w01, w10, w11);
  const float2* xs = x + (size_t)(p * ZT + z) * HW2;
  float2 v00 = xs[y0 * WG + x0], v01 = xs[y0 * WG + x1];
  float2 v10 = xs[y1 * WG + x0], v11 = xs[y1 * WG + x1];
  float2 o;
  o.x = v00.x * w00 + v01.x * w01 + v10.x * w10 + v11.x * w11;
  o.y = v00.y * w00 + v01.y * w01 + v10.y * w10 + v11.y * w11;
  warped[gid] = o;
  // TV gradient
  float2 xc = xs[hw];
  float tre = 0.f, tim = 0.f;
  if (h > 0){
    float2 n = xs[hw - WG];
    float dr = xc.x - n.x, di = xc.y - n.y;
    float r = sqrtf(dr * dr + di * di + 1e-8f);
    tre += dr / r; tim += di / r;
  }
  if (h < HG - 1){
    float2 n = xs[hw + WG];
    float dr = n.x - xc.x, di = n.y - xc.y;
    float r = sqrtf(dr * dr + di * di + 1e-8f);
    tre -= dr / r; tim -= di / r;
  }
  if (w > 0){
    float2 n = xs[hw - 1];
    float dr = xc.x - n.x, di = xc.y - n.y;
    float r = sqrtf(dr * dr + di * di + 1e-8f);
    tre += dr / r; tim += di / r;
  }
  if (w < WG - 1){
    float2 n = xs[hw + 1];
    float dr = n.x - xc.x, di = n.y - xc.y;
    float r = sqrtf(dr * dr + di * di + 1e-8f);
    tre -= dr / r; tim -= di / r;
  }
  gtv[gid] = make_float2(tre, -tim);
}

// row FFT forward: 8 rows of one slice per block (8 waves); output TRANSPOSED + bf16-packed:
// FT_[sl][w][h] (addr = sl*HW2 + w*HG + h), 4 B per complex.
__global__ __launch_bounds__(512) void k_fft_row_fwd(const float2* __restrict__ warped, const float2* __restrict__ csm,
                                                     unsigned* __restrict__ FT_, int p0){
  __shared__ float2 seg[8 * LSTR];
  FT f = ft_init();
  int wid = threadIdx.x >> 6, l = f.lane;
  int hg = blockIdx.x % 40; int sl = blockIdx.x / 40;      // sl = (pp*CHN + c)*ZE + zz
  int zz = sl % ZE; int s2 = sl / ZE; int c = s2 % CHN; int pp = s2 / CHN;
  int p = p0 + pp; int z = zz + 1;
  int h = hg * 8 + wid;
  const float2* wr = warped + ((size_t)(p * ZE + zz)) * HW2 + (size_t)h * WG;
  const float2* cs = csm + ((size_t)(c * ZT + z)) * HW2 + (size_t)h * WG;
  float sgn = ((h + l) & 1) ? -1.f : 1.f;
  float2 a[5];
  #pragma unroll
  for (int q = 0; q < 5; q++){
    float2 v = cmul(wr[64 * q + l], cs[64 * q + l]);
    a[q] = make_float2(v.x * sgn, v.y * sgn);
  }
  fft320w(a, f, seg + wid * LSTR);
  __syncthreads();
  unsigned* out = FT_ + (size_t)sl * HW2 + hg * 8;         // + w*HG later
  for (int i = threadIdx.x; i < 8 * WG; i += 512){
    int w = i >> 3; int hh = i & 7;
    out[(size_t)w * HG + hh] = pk(seg[hh * LSTR + w]);
  }
}

// fused forward: per block, TWO adjacent slices (same phase -> shared permx/xbnd) x
// (8 owned + 1 overlap) columns. Per wave, FFTs come in independent slice-pairs ->
// ILP-2 across the dependent shuffle chains. Sampling computes corners once per k-point
// and samples both slices. est written raw in x-sorted order.
__global__ __launch_bounds__(256) void k_fft_col_sample(const unsigned* __restrict__ FT_, const float4* __restrict__ permx,
                                                        const unsigned* __restrict__ xbnd, float2* __restrict__ est,
                                                        unsigned int* __restrict__ dmax, int p0){
  __shared__ float2 seg[2][9 * LSTR];   // 46,224 B -> 3 blocks/CU
  FT f = ft_init();
  int tid = threadIdx.x; int wid = tid >> 6, l = f.lane;
  int cg = blockIdx.x % 40; int pr = blockIdx.x / 40;       // slice pair (shares pp,c)
  int sl0 = pr * 2;
  int s2 = sl0 / ZE; int pp = s2 / CHN;
  int p = p0 + pp;
  int cbase = cg * 8;
  const int ncol = (cbase + 8 <= WG - 1) ? 9 : 8;
  const unsigned* Fs0 = FT_ + (size_t)sl0 * HW2 + (size_t)cbase * HG;
  const unsigned* Fs1 = Fs0 + HW2;
  // load both slices' columns (wave-uniform guards; clamped duplicate col is benign)
  unsigned raw0[3][5], raw1[3][5];
  #pragma unroll
  for (int cc = 0; cc < 3; cc++){
    int col = cc * 4 + wid;
    if (col < 9){
      int colc = min(col, ncol - 1);
      const unsigned* s0 = Fs0 + (size_t)colc * HG;
      const unsigned* s1 = Fs1 + (size_t)colc * HG;
      #pragma unroll
      for (int q = 0; q < 5; q++){ raw0[cc][q] = s0[64 * q + l]; raw1[cc][q] = s1[64 * q + l]; }
    }
  }
  // FFT pairs: slice0/slice1 of same column are independent -> back-to-back straight-line
  #pragma unroll
  for (int cc = 0; cc < 3; cc++){
    int col = cc * 4 + wid;
    if (col < 9){
      int colc = min(col, ncol - 1);
      float2 a0[5], a1[5];
      #pragma unroll
      for (int q = 0; q < 5; q++){ a0[q] = upk(raw0[cc][q]); a1[q] = upk(raw1[cc][q]); }
      fft320w(a0, f, seg[0] + colc * LSTR);
      fft320w(a1, f, seg[1] + colc * LSTR);
    }
  }
  __syncthreads();
  // sample both slices from LDS; corners computed once per k-point
  int lo = (int)xbnd[p * (WG + 1) + cbase];
  int hi = (int)xbnd[p * (WG + 1) + min(cbase + 8, WG)];
  float2* eb0 = est + ((size_t)(p0 * CHN * ZE) + sl0) * NKP;
  float2* eb1 = eb0 + NKP;
  const float4* px = permx + p * NKP;
  float md2 = 0.f;
  for (int j = lo + tid; j < hi; j += 256){
    float4 e4 = px[j];
    int y0, x0, y1, x1; float w00, w01, w10, w11;
    corners(e4.y, e4.z, y0, x0, y1, x1, w00, w01, w10, w11);
    int lc0 = x0 - cbase, lc1 = x1 - cbase;
    {
      float2 v00 = seg[0][lc0 * LSTR + y0], v01 = seg[0][lc1 * LSTR + y0];
      float2 v10 = seg[0][lc0 * LSTR + y1], v11 = seg[0][lc1 * LSTR + y1];
      float2 e;
      e.x = v00.x * w00 + v01.x * w01 + v10.x * w10 + v11.x * w11;
      e.y = v00.y * w00 + v01.y * w01 + v10.y * w10 + v11.y * w11;
      eb0[j] = e;
      md2 = fmaxf(md2, e.x * e.x + e.y * e.y);
    }
    {
      float2 v00 = seg[1][lc0 * LSTR + y0], v01 = seg[1][lc1 * LSTR + y0];
      float2 v10 = seg[1][lc0 * LSTR + y1], v11 = seg[1][lc1 * LSTR + y1];
      float2 e;
      e.x = v00.x * w00 + v01.x * w01 + v10.x * w10 + v11.x * w11;
      e.y = v00.y * w00 + v01.y * w01 + v10.y * w10 + v11.y * w11;
      eb1[j] = e;
      md2 = fmaxf(md2, e.x * e.x + e.y * e.y);
    }
  }
  for (int off = 32; off > 0; off >>= 1) md2 = fmaxf(md2, __shfl_down(md2, off, 64));
  if ((tid & 63) == 0 && md2 > 0.f) atomicMax(dmax, __float_as_uint(md2));
}

// backward: fused { weights (est->G on the fly) + zero tile + x-bucketed corner scatter
// (LDS atomics) + per-wave column DFT^T }. F written NORMAL layout, bf16-packed.
__global__ __launch_bounds__(256) void k_fft_col_scatter(const float2* __restrict__ est, const float2* __restrict__ kdata,
                                                         const float4* __restrict__ permx,
                                                         const unsigned* __restrict__ xbnd,
                                                         const unsigned int* __restrict__ dmax,
                                                         unsigned* __restrict__ F, int p0){
  __shared__ float2 ld[16 * LSTR];
  FT f = ft_init();
  int tid = threadIdx.x; int wid = tid >> 6, l = f.lane;
  int cg = blockIdx.x % 20; int sl = blockIdx.x / 20;       // local slice
  int zz = sl % ZE; int s2 = sl / ZE; int c = s2 % CHN; int pp = s2 / CHN;
  int p = p0 + pp; int z = zz + 1;
  for (int i = tid; i < 16 * LSTR; i += 256) ld[i] = make_float2(0.f, 0.f);
  __syncthreads();
  float md = sqrtf(__uint_as_float(*dmax));
  int cbase = cg * 16;
  int lo = (cbase > 0) ? (int)xbnd[p * (WG + 1) + cbase - 1] : 0;
  int hi = (int)xbnd[p * (WG + 1) + min(cbase + 16, WG)];
  const float2* Es = est + ((size_t)(p0 * CHN * ZE) + sl) * NKP;
  const float2* kd = kdata + ((size_t)(p * CHN + c) * ZT + z) * NKP;
  const float4* px = permx + p * NKP;
  for (int j = lo + tid; j < hi; j += 256){
    float4 e4 = px[j];
    int k = (int)__float_as_uint(e4.x);
    int y0, x0, y1, x1; float w00, w01, w10, w11;
    corners(e4.y, e4.z, y0, x0, y1, x1, w00, w01, w10, w11);
    float2 e = Es[j];
    float det = sqrtf(e.x * e.x + e.y * e.y);
    float wv = 1.0f / (det / md + EPS_C);
    float sc = wv * wv * INV_N;
    float2 y = kd[k];
    float2 gv = make_float2(sc * (e.x - y.x), -sc * (e.y - y.y));
    int c0 = x0 - cbase, c1 = x1 - cbase;
    if ((unsigned)c0 < 16u){
      atomicAdd(&ld[c0 * LSTR + y0].x, gv.x * w00); atomicAdd(&ld[c0 * LSTR + y0].y, gv.y * w00);
      atomicAdd(&ld[c0 * LSTR + y1].x, gv.x * w10); atomicAdd(&ld[c0 * LSTR + y1].y, gv.y * w10);
    }
    if ((unsigned)c1 < 16u){
      atomicAdd(&ld[c1 * LSTR + y0].x, gv.x * w01); atomicAdd(&ld[c1 * LSTR + y0].y, gv.y * w01);
      atomicAdd(&ld[c1 * LSTR + y1].x, gv.x * w11); atomicAdd(&ld[c1 * LSTR + y1].y, gv.y * w11);
    }
  }
  __syncthreads();
  #pragma unroll
  for (int cc = 0; cc < 4; cc++){
    float2* base = ld + (wid * 4 + cc) * LSTR;
    float2 a[5];
    #pragma unroll
    for (int q = 0; q < 5; q++) a[q] = base[64 * q + l];
    fft320w(a, f, base);
  }
  __syncthreads();
  unsigned* Fs = F + (size_t)sl * HW2 + cbase;
  for (int i = tid; i < 5120; i += 256){ int h = i >> 4, col = i & 15; Fs[h * WG + col] = pk(ld[col * LSTR + h]); }
}

// transpose row pass: 8 waves = 8 coils of one (pp,zz,h) row; epilogue *(-1)^(h+w), *csm, coil sum
__global__ __launch_bounds__(512) void k_fft_row_bwd(const unsigned* __restrict__ F, const float2* __restrict__ csm,
                                                     float2* __restrict__ gwarped, int p0){
  __shared__ float2 seg[8 * LSTR];
  FT f = ft_init();
  int tid = threadIdx.x; int c = tid >> 6, l = f.lane;
  int bid = blockIdx.x;                          // over np*ZE*HG
  int h = bid % HG; int b2 = bid / HG;
  int zz = b2 % ZE; int pp = b2 / ZE;
  int p = p0 + pp; int z = zz + 1;
  const unsigned* Fl = F + ((size_t)((pp * CHN + c) * ZE + zz)) * HW2 + (size_t)h * WG;
  float2 a[5];
  #pragma unroll
  for (int q = 0; q < 5; q++) a[q] = upk(Fl[64 * q + l]);
  fft320w(a, f, seg + c * LSTR);
  __syncthreads();
  if (tid < WG){
    int w = tid;
    float2 acc = make_float2(0.f, 0.f);
    #pragma unroll
    for (int cc = 0; cc < 8; cc++){
      cmac(acc, seg[cc * LSTR + w], csm[((size_t)(cc * ZT + z)) * HW2 + (size_t)h * WG + w]);
    }
    float sg = ((h + w) & 1) ? -1.f : 1.f;
    gwarped[((size_t)(p * ZE + zz)) * HW2 + (size_t)h * WG + w] = make_float2(acc.x * sg, acc.y * sg);
  }
}

// ---------------- gather-tiled warp adjoint + fused gradient update ----------------
#define TRG 8
#define HAG 8
__global__ __launch_bounds__(512) void k_warpadj_update(const float2* __restrict__ gw, const float* __restrict__ mvf,
                                                        const float2* __restrict__ gtv, const float* __restrict__ stdp,
                                                        float2* __restrict__ x,
                                                        uint4* __restrict__ fb, unsigned int* __restrict__ fbcnt){
  __shared__ float lt[TRG * WG * 2];   // 20480 B
  int tid = threadIdx.x;
  int bid = blockIdx.x;                    // pz*40 + tile
  int tile = bid % 40; int pz = bid / 40;
  int zz = pz % ZE, p = pz / ZE, z = zz + 1;
  int R = tile * TRG;
  for (int i = tid; i < TRG * WG * 2; i += 512) lt[i] = 0.f;
  __syncthreads();
  const float* mvy = mvf + ((size_t)(p * 2 + 0) * ZT + z) * HW2;
  const float* mvx = mvy + (size_t)ZT * HW2;
  const float2* g = gw + (size_t)pz * HW2;
  const size_t xbase = (size_t)(p * ZT + z) * HW2;
  int wlo = max(R - HAG, 0), whi = min(R + TRG + HAG, HG);
  int npx = (whi - wlo) * WG;
  int base0 = wlo * WG;
  int i = tid;
  float fy = 0.f, fx = 0.f; float2 gv = make_float2(0.f, 0.f);
  if (i < npx){ fy = mvy[base0 + i]; fx = mvx[base0 + i]; gv = g[base0 + i]; }
  while (i < npx){
    int inx = i + 512;
    float fy2 = 0.f, fx2 = 0.f; float2 gv2 = make_float2(0.f, 0.f);
    if (inx < npx){ fy2 = mvy[base0 + inx]; fx2 = mvx[base0 + inx]; gv2 = g[base0 + inx]; }
    int hh = i / WG; int w = i - hh * WG;
    int h = wlo + hh;
    float gy = fminf(fmaxf((float)h + fy, 0.f), 319.f);
    float gx = fminf(fmaxf((float)w + fx, 0.f), 319.f);
    int y0, x0, y1, x1; float w00, w01, w10, w11;
    corners(gy, gx, y0, x0, y1, x1, w00, w01, w10, w11);
    bool owner = (h >= R) && (h < R + TRG);
    #define PROC(Y, XC, WT) { \
      int ry = (Y) - R; \
      if ((unsigned)ry < (unsigned)TRG){ \
        atomicAdd(&lt[(ry * WG + (XC)) * 2 + 0], gv.x * (WT)); \
        atomicAdd(&lt[(ry * WG + (XC)) * 2 + 1], gv.y * (WT)); \
      } else if (owner){ \
        int Ry = (Y) & ~(TRG - 1); \
        if (h < Ry - HAG || h >= Ry + TRG + HAG){ \
          unsigned slot = atomicAdd(fbcnt, 1u); \
          if (slot < FBCAP) fb[slot] = make_uint4((unsigned)(xbase + (size_t)(Y) * WG + (XC)), \
                                                  __float_as_uint(gv.x * (WT)), __float_as_uint(gv.y * (WT)), 0u); \
        } \
      } \
    }
    PROC(y0, x0, w00); PROC(y0, x1, w01); PROC(y1, x0, w10); PROC(y1, x1, w11);
    #undef PROC
    i = inx; fy = fy2; fx = fx2; gv = gv2;
  }
  __syncthreads();
  float s = stdp[0];
  const float2* gt = gtv + (size_t)pz * HW2;
  for (int i2 = tid; i2 < TRG * WG; i2 += 512){
    int yy = i2 / WG; int w = i2 - yy * WG;
    int hw = (R + yy) * WG + w;
    float2 xv = x[xbase + hw];
    float2 tv = gt[hw];
    xv.x -= GAMMA_C * lt[i2 * 2 + 0] + TAU_C * s * tv.x;
    xv.y -= GAMMA_C * lt[i2 * 2 + 1] + TAU_C * s * tv.y;
    x[xbase + hw] = xv;
  }
}

// apply rare out-of-halo contributions: x[idx] -= GAMMA * val
__global__ __launch_bounds__(256) void k_fixup(const uint4* __restrict__ fb, const unsigned int* __restrict__ fbcnt,
                                               float2* __restrict__ x){
  unsigned n = *fbcnt; if (n > FBCAP) n = FBCAP;
  for (unsigned i = blockIdx.x * 256 + threadIdx.x; i < n; i += gridDim.x * 256){
    uint4 e = fb[i];
    atomicAdd(&x[e.x].x, -GAMMA_C * __uint_as_float(e.y));
    atomicAdd(&x[e.x].y, -GAMMA_C * __uint_as_float(e.z));
  }
}

// ---------------- host ----------------
extern "C" void kernel_launch(void* const* d_in, const int* in_sizes, int n_in,
                              void* d_out, int out_size, void* d_ws, size_t ws_size,
                              hipStream_t stream) {
  const float2* kdata = (const float2*)d_in[0];
  const float*  traj  = (const float*) d_in[1];
  const float2* img0  = (const float2*)d_in[2];
  const float*  mvf   = (const float*) d_in[3];
  const float2* csm   = (const float2*)d_in[4];
  const float*  stdp  = (const float*) d_in[5];
  float2* x = (float2*)d_out;

  const size_t F_B  = (size_t)CHN * ZE * HW2 * 4;        // 19,660,800 (bf16-packed complex)
  const size_t W_B  = (size_t)PH * ZE * HW2 * 8;         // 19,660,800
  const size_t E_B  = (size_t)PH * CHN * ZE * NKP * 8;   //  6,291,456
  const size_t FB_B = (size_t)FBCAP * 16;                //  2,097,152
  const size_t P_B  = (size_t)PH * NKP * 16;             //    262,144
  const size_t SORT_B = P_B + 4 * 8192;

  size_t need_big = 4 * F_B + 2 * W_B + E_B + 512 + FB_B + SORT_B;   // ~128 MB
  const int NP = (ws_size >= need_big) ? 4 : 1;

  char* cur = (char*)d_ws;
  unsigned* F    = (unsigned*)cur;  cur += (size_t)NP * F_B;  // fwd: transposed; bwd: normal (bf16 packed)
  float2* warped = (float2*)cur;  cur += W_B;                 // also holds gwarped
  float2* est    = (float2*)cur;  cur += E_B;
  float2* gtvb   = (float2*)cur;  cur += W_B;
  unsigned int* dmax  = (unsigned int*)cur; cur += 128;
  unsigned int* fbcnt = (unsigned int*)cur; cur += 128;
  uint4* fb           = (uint4*)cur;        cur += FB_B;
  float4* permx       = (float4*)cur;       cur += P_B;
  unsigned* xhist     = (unsigned*)cur;     cur += 8192;
  unsigned* xcur      = (unsigned*)cur;     cur += 8192;
  unsigned* xbnd      = (unsigned*)cur;     cur += 8192;

  k_init<<<12800, 256, 0, stream>>>(img0, x, PH * ZT * HW2);
  // build x-sorted k-point list (traj constant across iterations)
  hipMemsetAsync(xhist, 0, 8192, stream);
  k_khist<<<64, 256, 0, stream>>>(traj, xhist);
  k_kscan<<<1, 64, 0, stream>>>(xhist, xcur, xbnd);
  k_kperm<<<64, 256, 0, stream>>>(traj, xcur, permx);

  for (int it = 0; it < 3; it++){
    k_warp_tv<<<9600, 256, 0, stream>>>(x, mvf, warped, gtvb, dmax, fbcnt);
    for (int p0 = 0; p0 < PH; p0 += NP){
      k_fft_row_fwd   <<<NP * 1920, 512, 0, stream>>>(warped, csm, F, p0);
      k_fft_col_sample<<<NP *  960, 256, 0, stream>>>(F, permx, xbnd, est, dmax, p0);  // 2 slices/block
    }
    for (int p0 = 0; p0 < PH; p0 += NP){
      k_fft_col_scatter<<<NP *  960, 256, 0, stream>>>(est, kdata, permx, xbnd, dmax, F, p0);
      k_fft_row_bwd    <<<NP * 1920, 512, 0, stream>>>(F, csm, warped, p0);
    }
    k_warpadj_update<<<960, 512, 0, stream>>>(warped, mvf, gtvb, stdp, x, fb, fbcnt);
    k_fixup<<<16, 256, 0, stream>>>(fb, fbcnt, x);
  }
}

// Round 16
// 1538.517 us; speedup vs baseline: 1.2078x; 1.0058x over previous
//
#include <hip/hip_runtime.h>
#include <math.h>

// ---------------- problem constants ----------------
#define PH   4
#define CHN  8
#define ZT   8
#define ZE   6          // effective z slices: z in [1,7)
#define HG   320
#define WG   320
#define HW2  102400     // 320*320
#define NKP  4096
#define LSTR 321        // LDS line stride (pad +1)
#define FBCAP 131072u   // fallback list capacity (entries)

constexpr float GAMMA_C = 0.1f;
constexpr float TAU_C   = 0.2f;
constexpr float EPS_C   = 0.01f;
constexpr float INV_N   = 1.0f / 786432.0f;   // PH*CHN*ZE*NKP
#define TWO_PI_F 6.28318530717958647692f

// W5^j = e^{-2*pi*i*j/5}
constexpr float W5R[5] = { 1.f,  0.30901699f, -0.80901699f, -0.80901699f,  0.30901699f};
constexpr float W5I[5] = { 0.f, -0.95105652f, -0.58778525f,  0.58778525f,  0.95105652f};

// ---------------- complex helpers ----------------
__device__ __forceinline__ float2 cmul(float2 a, float2 b){
  return make_float2(a.x*b.x - a.y*b.y, a.x*b.y + a.y*b.x);
}
__device__ __forceinline__ void cmac(float2& d, float2 a, float2 b){
  d.x = fmaf(a.x, b.x, fmaf(-a.y, b.y, d.x));
  d.y = fmaf(a.x, b.y, fmaf( a.y, b.x, d.y));
}

// bf16-packed complex: re in low 16, im in high 16 (round-to-nearest-even)
__device__ __forceinline__ unsigned pk(float2 v){
  unsigned ua = __float_as_uint(v.x), ub = __float_as_uint(v.y);
  ua = (ua + 0x7FFFu + ((ua >> 16) & 1u)) >> 16;
  ub = (ub + 0x7FFFu + ((ub >> 16) & 1u)) >> 16;
  return ua | (ub << 16);
}
__device__ __forceinline__ float2 upk(unsigned v){
  return make_float2(__uint_as_float(v << 16), __uint_as_float(v & 0xFFFF0000u));
}

__device__ __forceinline__ void corners(float gy, float gx, int& y0, int& x0, int& y1, int& x1,
                                        float& w00, float& w01, float& w10, float& w11){
  float y0f = floorf(gy), x0f = floorf(gx);
  float wy = gy - y0f, wx = gx - x0f;
  y0 = (int)y0f; x0 = (int)x0f;
  y1 = min(y0 + 1, HG - 1); x1 = min(x0 + 1, WG - 1);
  w00 = (1.f - wy) * (1.f - wx);
  w01 = (1.f - wy) * wx;
  w10 = wy * (1.f - wx);
  w11 = wy * wx;
}

__device__ __forceinline__ void traj_to_grid(float ty, float tx, float& gy, float& gx){
  gy = fminf(fmaxf((ty / TWO_PI_F + 0.5f) * 320.f, 0.f), 319.f);
  gx = fminf(fmaxf((tx / TWO_PI_F + 0.5f) * 320.f, 0.f), 319.f);
}

// ---------------- in-register 320-pt FFT: one wave per line, N = 5 x 64 ----------------
// (verified rounds 5-15). Lane l stores X[5*br6(l)+r]; un-permuted via LDS seg.
struct FT {
  float2 t1, t2, t3, t4;
  float2 tw0, tw1, tw2, tw3, tw4;
  int br5, lane;
};

__device__ __forceinline__ FT ft_init(){
  FT f; int l = (int)(threadIdx.x & 63); f.lane = l;
  sincosf(-TWO_PI_F * (float)l * (1.0f/320.0f), &f.t1.y, &f.t1.x);
  f.t2 = cmul(f.t1, f.t1); f.t3 = cmul(f.t2, f.t1); f.t4 = cmul(f.t2, f.t2);
  sincosf(-TWO_PI_F * (float)(l & 31) * (1.0f/64.0f), &f.tw0.y, &f.tw0.x);
  sincosf(-TWO_PI_F * (float)(l & 15) * (1.0f/32.0f), &f.tw1.y, &f.tw1.x);
  sincosf(-TWO_PI_F * (float)(l &  7) * (1.0f/16.0f), &f.tw2.y, &f.tw2.x);
  sincosf(-TWO_PI_F * (float)(l &  3) * (1.0f/ 8.0f), &f.tw3.y, &f.tw3.x);
  f.tw4 = (l & 1) ? make_float2(0.f, -1.f) : make_float2(1.f, 0.f);
  int br = ((l&1)<<5) | ((l&2)<<3) | ((l&4)<<1) | ((l&8)>>1) | ((l&16)>>3) | ((l&32)>>5);
  f.br5 = 5 * br;
  return f;
}

template<int H>
__device__ __forceinline__ void bfly(float2& v, float2 tw, int lane){
  float px = __shfl_xor(v.x, H, 64);
  float py = __shfl_xor(v.y, H, 64);
  bool up = (lane & H) != 0;
  float ax = up ? px : v.x, ay = up ? py : v.y;
  float bx = up ? v.x : px, by = up ? v.y : py;
  float dx = ax - bx,  dy = ay - by;
  float mx = fmaf(dx, tw.x, -dy * tw.y);
  float my = fmaf(dx, tw.y,  dy * tw.x);
  v.x = up ? mx : (ax + bx);
  v.y = up ? my : (ay + by);
}

__device__ __forceinline__ float2 fft320_core(float2 v, const FT& f, int stage_r);  // fwd decl unused

__device__ __forceinline__ void fft320w(const float2 a[5], const FT& f, float2* __restrict__ seg){
  float2 z[5];
  #pragma unroll
  for (int r = 0; r < 5; r++){
    float2 acc = a[0];
    #pragma unroll
    for (int q = 1; q < 5; q++){
      const int j = (q * r) % 5;
      cmac(acc, a[q], make_float2(W5R[j], W5I[j]));
    }
    z[r] = acc;
  }
  z[1] = cmul(z[1], f.t1); z[2] = cmul(z[2], f.t2);
  z[3] = cmul(z[3], f.t3); z[4] = cmul(z[4], f.t4);
  #pragma unroll
  for (int r = 0; r < 5; r++){
    float2 v = z[r];
    bfly<32>(v, f.tw0, f.lane);
    bfly<16>(v, f.tw1, f.lane);
    bfly< 8>(v, f.tw2, f.lane);
    bfly< 4>(v, f.tw3, f.lane);
    bfly< 2>(v, f.tw4, f.lane);
    {
      float px = __shfl_xor(v.x, 1, 64);
      float py = __shfl_xor(v.y, 1, 64);
      bool up = (f.lane & 1) != 0;
      float ax = up ? px : v.x, ay = up ? py : v.y;
      float bx = up ? v.x : px, by = up ? v.y : py;
      v.x = up ? (ax - bx) : (ax + bx);
      v.y = up ? (ay - by) : (ay + by);
    }
    seg[f.br5 + r] = v;
  }
}

// same, but stores bf16-packed into an LDS unsigned array
__device__ __forceinline__ void fft320w_pk(const float2 a[5], const FT& f, unsigned* __restrict__ seg){
  float2 z[5];
  #pragma unroll
  for (int r = 0; r < 5; r++){
    float2 acc = a[0];
    #pragma unroll
    for (int q = 1; q < 5; q++){
      const int j = (q * r) % 5;
      cmac(acc, a[q], make_float2(W5R[j], W5I[j]));
    }
    z[r] = acc;
  }
  z[1] = cmul(z[1], f.t1); z[2] = cmul(z[2], f.t2);
  z[3] = cmul(z[3], f.t3); z[4] = cmul(z[4], f.t4);
  #pragma unroll
  for (int r = 0; r < 5; r++){
    float2 v = z[r];
    bfly<32>(v, f.tw0, f.lane);
    bfly<16>(v, f.tw1, f.lane);
    bfly< 8>(v, f.tw2, f.lane);
    bfly< 4>(v, f.tw3, f.lane);
    bfly< 2>(v, f.tw4, f.lane);
    {
      float px = __shfl_xor(v.x, 1, 64);
      float py = __shfl_xor(v.y, 1, 64);
      bool up = (f.lane & 1) != 0;
      float ax = up ? px : v.x, ay = up ? py : v.y;
      float bx = up ? v.x : px, by = up ? v.y : py;
      v.x = up ? (ax - bx) : (ax + bx);
      v.y = up ? (ay - by) : (ay + by);
    }
    seg[f.br5 + r] = pk(v);
  }
}

// ---------------- k-point x-sorting (once per call; traj constant across iterations) --------
__global__ __launch_bounds__(256) void k_khist(const float* __restrict__ traj, unsigned* __restrict__ xhist){
  int gid = blockIdx.x * 256 + threadIdx.x;
  if (gid >= PH * NKP) return;
  int p = gid >> 12, k = gid & (NKP - 1);
  float gy, gx;
  traj_to_grid(traj[(p * 2 + 0) * NKP + k], traj[(p * 2 + 1) * NKP + k], gy, gx);
  atomicAdd(&xhist[p * WG + (int)floorf(gx)], 1u);
}

__global__ void k_kscan(const unsigned* __restrict__ xhist, unsigned* __restrict__ xcur,
                        unsigned* __restrict__ xbnd){
  int p = threadIdx.x;
  if (p < PH){
    unsigned acc = 0;
    for (int b = 0; b < WG; b++){ xcur[p * WG + b] = acc; xbnd[p * (WG + 1) + b] = acc; acc += xhist[p * WG + b]; }
    xbnd[p * (WG + 1) + WG] = acc;
  }
}

__global__ __launch_bounds__(256) void k_kperm(const float* __restrict__ traj, unsigned* __restrict__ xcur,
                                               float4* __restrict__ permx){
  int gid = blockIdx.x * 256 + threadIdx.x;
  if (gid >= PH * NKP) return;
  int p = gid >> 12, k = gid & (NKP - 1);
  float gy, gx;
  traj_to_grid(traj[(p * 2 + 0) * NKP + k], traj[(p * 2 + 1) * NKP + k], gy, gx);
  unsigned sx = atomicAdd(&xcur[p * WG + (int)floorf(gx)], 1u);
  permx[p * NKP + sx] = make_float4(__uint_as_float((unsigned)k), gy, gx, 0.f);
}

// ---------------- kernels ----------------
__global__ __launch_bounds__(256) void k_init(const float2* __restrict__ img0, float2* __restrict__ x, int n){
  int i = blockIdx.x * 256 + threadIdx.x;
  if (i < n){
    float2 v = img0[i];
    v.x = isnan(v.x) ? 0.f : fminf(fmaxf(v.x, -3.4028235e38f), 3.4028235e38f);
    v.y = isnan(v.y) ? 0.f : fminf(fmaxf(v.y, -3.4028235e38f), 3.4028235e38f);
    x[i] = v;
  }
}

// fused: warped = bilinear-warp(x, mvf); gtv = conj(TV-grad(x)); also zeroes dmax/fbcnt
__global__ __launch_bounds__(256) void k_warp_tv(const float2* __restrict__ x, const float* __restrict__ mvf,
                                                 float2* __restrict__ warped, float2* __restrict__ gtv,
                                                 unsigned int* __restrict__ dmax, unsigned int* __restrict__ fbcnt){
  if (blockIdx.x == 0 && threadIdx.x == 0){ *dmax = 0u; *fbcnt = 0u; }
  int gid = blockIdx.x * 256 + threadIdx.x;          // over PH*ZE*HW2
  int hw = gid % HW2;
  int pz = gid / HW2;
  int zz = pz % ZE, p = pz / ZE, z = zz + 1;
  int h = hw / WG, w = hw - h * WG;
  const float* mv = mvf + ((size_t)(p * 2 + 0) * ZT + z) * HW2;
  float fy = mv[hw];
  float fx = mv[(size_t)ZT * HW2 + hw];
  float gy = fminf(fmaxf((float)h + fy, 0.f), 319.f);
  float gx = fminf(fmaxf((float)w + fx, 0.f), 319.f);
  int y0, x0, y1, x1; float w00, w01, w10, w11;
  corners(gy, gx, y0, x0, y1, x1, w00, w01, w10, w11);
  const float2* xs = x + (size_t)(p * ZT + z) * HW2;
  float2 v00 = xs[y0 * WG + x0], v01 = xs[y0 * WG + x1];
  float2 v10 = xs[y1 * WG + x0], v11 = xs[y1 * WG + x1];
  float2 o;
  o.x = v00.x * w00 + v01.x * w01 + v10.x * w10 + v11.x * w11;
  o.y = v00.y * w00 + v01.y * w01 + v10.y * w10 + v11.y * w11;
  warped[gid] = o;
  // TV gradient
  float2 xc = xs[hw];
  float tre = 0.f, tim = 0.f;
  if (h > 0){
    float2 n = xs[hw - WG];
    float dr = xc.x - n.x, di = xc.y - n.y;
    float r = sqrtf(dr * dr + di * di + 1e-8f);
    tre += dr / r; tim += di / r;
  }
  if (h < HG - 1){
    float2 n = xs[hw + WG];
    float dr = n.x - xc.x, di = n.y - xc.y;
    float r = sqrtf(dr * dr + di * di + 1e-8f);
    tre -= dr / r; tim -= di / r;
  }
  if (w > 0){
    float2 n = xs[hw - 1];
    float dr = xc.x - n.x, di = xc.y - n.y;
    float r = sqrtf(dr * dr + di * di + 1e-8f);
    tre += dr / r; tim += di / r;
  }
  if (w < WG - 1){
    float2 n = xs[hw + 1];
    float dr = n.x - xc.x, di = n.y - xc.y;
    float r = sqrtf(dr * dr + di * di + 1e-8f);
    tre -= dr / r; tim -= di / r;
  }
  gtv[gid] = make_float2(tre, -tim);
}

// row FFT forward: 8 rows of one slice per block (8 waves); output TRANSPOSED + bf16-packed:
// FT_[sl][w][h] (addr = sl*HW2 + w*HG + h), 4 B per complex.
__global__ __launch_bounds__(512) void k_fft_row_fwd(const float2* __restrict__ warped, const float2* __restrict__ csm,
                                                     unsigned* __restrict__ FT_, int p0){
  __shared__ float2 seg[8 * LSTR];
  FT f = ft_init();
  int wid = threadIdx.x >> 6, l = f.lane;
  int hg = blockIdx.x % 40; int sl = blockIdx.x / 40;      // sl = (pp*CHN + c)*ZE + zz
  int zz = sl % ZE; int s2 = sl / ZE; int c = s2 % CHN; int pp = s2 / CHN;
  int p = p0 + pp; int z = zz + 1;
  int h = hg * 8 + wid;
  const float2* wr = warped + ((size_t)(p * ZE + zz)) * HW2 + (size_t)h * WG;
  const float2* cs = csm + ((size_t)(c * ZT + z)) * HW2 + (size_t)h * WG;
  float sgn = ((h + l) & 1) ? -1.f : 1.f;
  float2 a[5];
  #pragma unroll
  for (int q = 0; q < 5; q++){
    float2 v = cmul(wr[64 * q + l], cs[64 * q + l]);
    a[q] = make_float2(v.x * sgn, v.y * sgn);
  }
  fft320w(a, f, seg + wid * LSTR);
  __syncthreads();
  unsigned* out = FT_ + (size_t)sl * HW2 + hg * 8;         // + w*HG later
  for (int i = threadIdx.x; i < 8 * WG; i += 512){
    int w = i >> 3; int hh = i & 7;
    out[(size_t)w * HG + hh] = pk(seg[hh * LSTR + w]);
  }
}

// fused forward: per block, TWO adjacent slices x (8 owned + 1 overlap) columns.
// FFT pairs give ILP-2 across shuffle chains; spectrum stored bf16-packed in LDS (23.1 KB)
// for ~2x resident blocks. Sampling computes corners once per k-point, samples both slices.
__global__ __launch_bounds__(256) void k_fft_col_sample(const unsigned* __restrict__ FT_, const float4* __restrict__ permx,
                                                        const unsigned* __restrict__ xbnd, float2* __restrict__ est,
                                                        unsigned int* __restrict__ dmax, int p0){
  __shared__ unsigned seg[2][9 * LSTR];   // 23,112 B (bf16-packed spectrum)
  FT f = ft_init();
  int tid = threadIdx.x; int wid = tid >> 6, l = f.lane;
  int cg = blockIdx.x % 40; int pr = blockIdx.x / 40;       // slice pair (shares pp,c)
  int sl0 = pr * 2;
  int s2 = sl0 / ZE; int pp = s2 / CHN;
  int p = p0 + pp;
  int cbase = cg * 8;
  const int ncol = (cbase + 8 <= WG - 1) ? 9 : 8;
  const unsigned* Fs0 = FT_ + (size_t)sl0 * HW2 + (size_t)cbase * HG;
  const unsigned* Fs1 = Fs0 + HW2;
  // load both slices' columns (wave-uniform guards; clamped duplicate col is benign)
  unsigned raw0[3][5], raw1[3][5];
  #pragma unroll
  for (int cc = 0; cc < 3; cc++){
    int col = cc * 4 + wid;
    if (col < 9){
      int colc = min(col, ncol - 1);
      const unsigned* s0 = Fs0 + (size_t)colc * HG;
      const unsigned* s1 = Fs1 + (size_t)colc * HG;
      #pragma unroll
      for (int q = 0; q < 5; q++){ raw0[cc][q] = s0[64 * q + l]; raw1[cc][q] = s1[64 * q + l]; }
    }
  }
  // FFT pairs: slice0/slice1 of same column are independent -> back-to-back straight-line
  #pragma unroll
  for (int cc = 0; cc < 3; cc++){
    int col = cc * 4 + wid;
    if (col < 9){
      int colc = min(col, ncol - 1);
      float2 a0[5], a1[5];
      #pragma unroll
      for (int q = 0; q < 5; q++){ a0[q] = upk(raw0[cc][q]); a1[q] = upk(raw1[cc][q]); }
      fft320w_pk(a0, f, seg[0] + colc * LSTR);
      fft320w_pk(a1, f, seg[1] + colc * LSTR);
    }
  }
  __syncthreads();
  // sample both slices from LDS; corners computed once per k-point
  int lo = (int)xbnd[p * (WG + 1) + cbase];
  int hi = (int)xbnd[p * (WG + 1) + min(cbase + 8, WG)];
  float2* eb0 = est + ((size_t)(p0 * CHN * ZE) + sl0) * NKP;
  float2* eb1 = eb0 + NKP;
  const float4* px = permx + p * NKP;
  float md2 = 0.f;
  for (int j = lo + tid; j < hi; j += 256){
    float4 e4 = px[j];
    int y0, x0, y1, x1; float w00, w01, w10, w11;
    corners(e4.y, e4.z, y0, x0, y1, x1, w00, w01, w10, w11);
    int lc0 = x0 - cbase, lc1 = x1 - cbase;
    {
      float2 v00 = upk(seg[0][lc0 * LSTR + y0]), v01 = upk(seg[0][lc1 * LSTR + y0]);
      float2 v10 = upk(seg[0][lc0 * LSTR + y1]), v11 = upk(seg[0][lc1 * LSTR + y1]);
      float2 e;
      e.x = v00.x * w00 + v01.x * w01 + v10.x * w10 + v11.x * w11;
      e.y = v00.y * w00 + v01.y * w01 + v10.y * w10 + v11.y * w11;
      eb0[j] = e;
      md2 = fmaxf(md2, e.x * e.x + e.y * e.y);
    }
    {
      float2 v00 = upk(seg[1][lc0 * LSTR + y0]), v01 = upk(seg[1][lc1 * LSTR + y0]);
      float2 v10 = upk(seg[1][lc0 * LSTR + y1]), v11 = upk(seg[1][lc1 * LSTR + y1]);
      float2 e;
      e.x = v00.x * w00 + v01.x * w01 + v10.x * w10 + v11.x * w11;
      e.y = v00.y * w00 + v01.y * w01 + v10.y * w10 + v11.y * w11;
      eb1[j] = e;
      md2 = fmaxf(md2, e.x * e.x + e.y * e.y);
    }
  }
  for (int off = 32; off > 0; off >>= 1) md2 = fmaxf(md2, __shfl_down(md2, off, 64));
  if ((tid & 63) == 0 && md2 > 0.f) atomicMax(dmax, __float_as_uint(md2));
}

// backward: fused { weights (est->G on the fly) + zero tile + x-bucketed corner scatter
// (LDS atomics) + per-wave column DFT^T }. F written NORMAL layout, bf16-packed.
__global__ __launch_bounds__(256) void k_fft_col_scatter(const float2* __restrict__ est, const float2* __restrict__ kdata,
                                                         const float4* __restrict__ permx,
                                                         const unsigned* __restrict__ xbnd,
                                                         const unsigned int* __restrict__ dmax,
                                                         unsigned* __restrict__ F, int p0){
  __shared__ float2 ld[16 * LSTR];
  FT f = ft_init();
  int tid = threadIdx.x; int wid = tid >> 6, l = f.lane;
  int cg = blockIdx.x % 20; int sl = blockIdx.x / 20;       // local slice
  int zz = sl % ZE; int s2 = sl / ZE; int c = s2 % CHN; int pp = s2 / CHN;
  int p = p0 + pp; int z = zz + 1;
  for (int i = tid; i < 16 * LSTR; i += 256) ld[i] = make_float2(0.f, 0.f);
  __syncthreads();
  float md = sqrtf(__uint_as_float(*dmax));
  int cbase = cg * 16;
  int lo = (cbase > 0) ? (int)xbnd[p * (WG + 1) + cbase - 1] : 0;
  int hi = (int)xbnd[p * (WG + 1) + min(cbase + 16, WG)];
  const float2* Es = est + ((size_t)(p0 * CHN * ZE) + sl) * NKP;
  const float2* kd = kdata + ((size_t)(p * CHN + c) * ZT + z) * NKP;
  const float4* px = permx + p * NKP;
  for (int j = lo + tid; j < hi; j += 256){
    float4 e4 = px[j];
    int k = (int)__float_as_uint(e4.x);
    int y0, x0, y1, x1; float w00, w01, w10, w11;
    corners(e4.y, e4.z, y0, x0, y1, x1, w00, w01, w10, w11);
    float2 e = Es[j];
    float det = sqrtf(e.x * e.x + e.y * e.y);
    float wv = 1.0f / (det / md + EPS_C);
    float sc = wv * wv * INV_N;
    float2 y = kd[k];
    float2 gv = make_float2(sc * (e.x - y.x), -sc * (e.y - y.y));
    int c0 = x0 - cbase, c1 = x1 - cbase;
    if ((unsigned)c0 < 16u){
      atomicAdd(&ld[c0 * LSTR + y0].x, gv.x * w00); atomicAdd(&ld[c0 * LSTR + y0].y, gv.y * w00);
      atomicAdd(&ld[c0 * LSTR + y1].x, gv.x * w10); atomicAdd(&ld[c0 * LSTR + y1].y, gv.y * w10);
    }
    if ((unsigned)c1 < 16u){
      atomicAdd(&ld[c1 * LSTR + y0].x, gv.x * w01); atomicAdd(&ld[c1 * LSTR + y0].y, gv.y * w01);
      atomicAdd(&ld[c1 * LSTR + y1].x, gv.x * w11); atomicAdd(&ld[c1 * LSTR + y1].y, gv.y * w11);
    }
  }
  __syncthreads();
  #pragma unroll
  for (int cc = 0; cc < 4; cc++){
    float2* base = ld + (wid * 4 + cc) * LSTR;
    float2 a[5];
    #pragma unroll
    for (int q = 0; q < 5; q++) a[q] = base[64 * q + l];
    fft320w(a, f, base);
  }
  __syncthreads();
  unsigned* Fs = F + (size_t)sl * HW2 + cbase;
  for (int i = tid; i < 5120; i += 256){ int h = i >> 4, col = i & 15; Fs[h * WG + col] = pk(ld[col * LSTR + h]); }
}

// transpose row pass: 8 waves = 8 coils of one (pp,zz,h) row; epilogue *(-1)^(h+w), *csm, coil sum
__global__ __launch_bounds__(512) void k_fft_row_bwd(const unsigned* __restrict__ F, const float2* __restrict__ csm,
                                                     float2* __restrict__ gwarped, int p0){
  __shared__ float2 seg[8 * LSTR];
  FT f = ft_init();
  int tid = threadIdx.x; int c = tid >> 6, l = f.lane;
  int bid = blockIdx.x;                          // over np*ZE*HG
  int h = bid % HG; int b2 = bid / HG;
  int zz = b2 % ZE; int pp = b2 / ZE;
  int p = p0 + pp; int z = zz + 1;
  const unsigned* Fl = F + ((size_t)((pp * CHN + c) * ZE + zz)) * HW2 + (size_t)h * WG;
  float2 a[5];
  #pragma unroll
  for (int q = 0; q < 5; q++) a[q] = upk(Fl[64 * q + l]);
  fft320w(a, f, seg + c * LSTR);
  __syncthreads();
  if (tid < WG){
    int w = tid;
    float2 acc = make_float2(0.f, 0.f);
    #pragma unroll
    for (int cc = 0; cc < 8; cc++){
      cmac(acc, seg[cc * LSTR + w], csm[((size_t)(cc * ZT + z)) * HW2 + (size_t)h * WG + w]);
    }
    float sg = ((h + w) & 1) ? -1.f : 1.f;
    gwarped[((size_t)(p * ZE + zz)) * HW2 + (size_t)h * WG + w] = make_float2(acc.x * sg, acc.y * sg);
  }
}

// ---------------- gather-tiled warp adjoint + fused gradient update ----------------
#define TRG 8
#define HAG 8
__global__ __launch_bounds__(512) void k_warpadj_update(const float2* __restrict__ gw, const float* __restrict__ mvf,
                                                        const float2* __restrict__ gtv, const float* __restrict__ stdp,
                                                        float2* __restrict__ x,
                                                        uint4* __restrict__ fb, unsigned int* __restrict__ fbcnt){
  __shared__ float lt[TRG * WG * 2];   // 20480 B
  int tid = threadIdx.x;
  int bid = blockIdx.x;                    // pz*40 + tile
  int tile = bid % 40; int pz = bid / 40;
  int zz = pz % ZE, p = pz / ZE, z = zz + 1;
  int R = tile * TRG;
  for (int i = tid; i < TRG * WG * 2; i += 512) lt[i] = 0.f;
  __syncthreads();
  const float* mvy = mvf + ((size_t)(p * 2 + 0) * ZT + z) * HW2;
  const float* mvx = mvy + (size_t)ZT * HW2;
  const float2* g = gw + (size_t)pz * HW2;
  const size_t xbase = (size_t)(p * ZT + z) * HW2;
  int wlo = max(R - HAG, 0), whi = min(R + TRG + HAG, HG);
  int npx = (whi - wlo) * WG;
  int base0 = wlo * WG;
  int i = tid;
  float fy = 0.f, fx = 0.f; float2 gv = make_float2(0.f, 0.f);
  if (i < npx){ fy = mvy[base0 + i]; fx = mvx[base0 + i]; gv = g[base0 + i]; }
  while (i < npx){
    int inx = i + 512;
    float fy2 = 0.f, fx2 = 0.f; float2 gv2 = make_float2(0.f, 0.f);
    if (inx < npx){ fy2 = mvy[base0 + inx]; fx2 = mvx[base0 + inx]; gv2 = g[base0 + inx]; }
    int hh = i / WG; int w = i - hh * WG;
    int h = wlo + hh;
    float gy = fminf(fmaxf((float)h + fy, 0.f), 319.f);
    float gx = fminf(fmaxf((float)w + fx, 0.f), 319.f);
    int y0, x0, y1, x1; float w00, w01, w10, w11;
    corners(gy, gx, y0, x0, y1, x1, w00, w01, w10, w11);
    bool owner = (h >= R) && (h < R + TRG);
    #define PROC(Y, XC, WT) { \
      int ry = (Y) - R; \
      if ((unsigned)ry < (unsigned)TRG){ \
        atomicAdd(&lt[(ry * WG + (XC)) * 2 + 0], gv.x * (WT)); \
        atomicAdd(&lt[(ry * WG + (XC)) * 2 + 1], gv.y * (WT)); \
      } else if (owner){ \
        int Ry = (Y) & ~(TRG - 1); \
        if (h < Ry - HAG || h >= Ry + TRG + HAG){ \
          unsigned slot = atomicAdd(fbcnt, 1u); \
          if (slot < FBCAP) fb[slot] = make_uint4((unsigned)(xbase + (size_t)(Y) * WG + (XC)), \
                                                  __float_as_uint(gv.x * (WT)), __float_as_uint(gv.y * (WT)), 0u); \
        } \
      } \
    }
    PROC(y0, x0, w00); PROC(y0, x1, w01); PROC(y1, x0, w10); PROC(y1, x1, w11);
    #undef PROC
    i = inx; fy = fy2; fx = fx2; gv = gv2;
  }
  __syncthreads();
  float s = stdp[0];
  const float2* gt = gtv + (size_t)pz * HW2;
  for (int i2 = tid; i2 < TRG * WG; i2 += 512){
    int yy = i2 / WG; int w = i2 - yy * WG;
    int hw = (R + yy) * WG + w;
    float2 xv = x[xbase + hw];
    float2 tv = gt[hw];
    xv.x -= GAMMA_C * lt[i2 * 2 + 0] + TAU_C * s * tv.x;
    xv.y -= GAMMA_C * lt[i2 * 2 + 1] + TAU_C * s * tv.y;
    x[xbase + hw] = xv;
  }
}

// apply rare out-of-halo contributions: x[idx] -= GAMMA * val
__global__ __launch_bounds__(256) void k_fixup(const uint4* __restrict__ fb, const unsigned int* __restrict__ fbcnt,
                                               float2* __restrict__ x){
  unsigned n = *fbcnt; if (n > FBCAP) n = FBCAP;
  for (unsigned i = blockIdx.x * 256 + threadIdx.x; i < n; i += gridDim.x * 256){
    uint4 e = fb[i];
    atomicAdd(&x[e.x].x, -GAMMA_C * __uint_as_float(e.y));
    atomicAdd(&x[e.x].y, -GAMMA_C * __uint_as_float(e.z));
  }
}

// ---------------- host ----------------
extern "C" void kernel_launch(void* const* d_in, const int* in_sizes, int n_in,
                              void* d_out, int out_size, void* d_ws, size_t ws_size,
                              hipStream_t stream) {
  const float2* kdata = (const float2*)d_in[0];
  const float*  traj  = (const float*) d_in[1];
  const float2* img0  = (const float2*)d_in[2];
  const float*  mvf   = (const float*) d_in[3];
  const float2* csm   = (const float2*)d_in[4];
  const float*  stdp  = (const float*) d_in[5];
  float2* x = (float2*)d_out;

  const size_t F_B  = (size_t)CHN * ZE * HW2 * 4;        // 19,660,800 (bf16-packed complex)
  const size_t W_B  = (size_t)PH * ZE * HW2 * 8;         // 19,660,800
  const size_t E_B  = (size_t)PH * CHN * ZE * NKP * 8;   //  6,291,456
  const size_t FB_B = (size_t)FBCAP * 16;                //  2,097,152
  const size_t P_B  = (size_t)PH * NKP * 16;             //    262,144
  const size_t SORT_B = P_B + 4 * 8192;

  size_t need_big = 4 * F_B + 2 * W_B + E_B + 512 + FB_B + SORT_B;   // ~128 MB
  const int NP = (ws_size >= need_big) ? 4 : 1;

  char* cur = (char*)d_ws;
  unsigned* F    = (unsigned*)cur;  cur += (size_t)NP * F_B;  // fwd: transposed; bwd: normal (bf16 packed)
  float2* warped = (float2*)cur;  cur += W_B;                 // also holds gwarped
  float2* est    = (float2*)cur;  cur += E_B;
  float2* gtvb   = (float2*)cur;  cur += W_B;
  unsigned int* dmax  = (unsigned int*)cur; cur += 128;
  unsigned int* fbcnt = (unsigned int*)cur; cur += 128;
  uint4* fb           = (uint4*)cur;        cur += FB_B;
  float4* permx       = (float4*)cur;       cur += P_B;
  unsigned* xhist     = (unsigned*)cur;     cur += 8192;
  unsigned* xcur      = (unsigned*)cur;     cur += 8192;
  unsigned* xbnd      = (unsigned*)cur;     cur += 8192;

  k_init<<<12800, 256, 0, stream>>>(img0, x, PH * ZT * HW2);
  // build x-sorted k-point list (traj constant across iterations)
  hipMemsetAsync(xhist, 0, 8192, stream);
  k_khist<<<64, 256, 0, stream>>>(traj, xhist);
  k_kscan<<<1, 64, 0, stream>>>(xhist, xcur, xbnd);
  k_kperm<<<64, 256, 0, stream>>>(traj, xcur, permx);

  for (int it = 0; it < 3; it++){
    k_warp_tv<<<9600, 256, 0, stream>>>(x, mvf, warped, gtvb, dmax, fbcnt);
    for (int p0 = 0; p0 < PH; p0 += NP){
      k_fft_row_fwd   <<<NP * 1920, 512, 0, stream>>>(warped, csm, F, p0);
      k_fft_col_sample<<<NP *  960, 256, 0, stream>>>(F, permx, xbnd, est, dmax, p0);  // 2 slices/block
    }
    for (int p0 = 0; p0 < PH; p0 += NP){
      k_fft_col_scatter<<<NP *  960, 256, 0, stream>>>(est, kdata, permx, xbnd, dmax, F, p0);
      k_fft_row_bwd    <<<NP * 1920, 512, 0, stream>>>(F, csm, warped, p0);
    }
    k_warpadj_update<<<960, 512, 0, stream>>>(warped, mvf, gtvb, stdp, x, fb, fbcnt);
    k_fixup<<<16, 256, 0, stream>>>(fb, fbcnt, x);
  }
}

// Round 17
// 1516.480 us; speedup vs baseline: 1.2253x; 1.0145x over previous
//
#include <hip/hip_runtime.h>
#include <math.h>

// ---------------- problem constants ----------------
#define PH   4
#define CHN  8
#define ZT   8
#define ZE   6          // effective z slices: z in [1,7)
#define HG   320
#define WG   320
#define HW2  102400     // 320*320
#define NKP  4096
#define LSTR 321        // LDS line stride (pad +1)
#define FBCAP 131072u   // fallback list capacity (entries)

constexpr float GAMMA_C = 0.1f;
constexpr float TAU_C   = 0.2f;
constexpr float EPS_C   = 0.01f;
constexpr float INV_N   = 1.0f / 786432.0f;   // PH*CHN*ZE*NKP
#define TWO_PI_F 6.28318530717958647692f

// W5^j = e^{-2*pi*i*j/5}
constexpr float W5R[5] = { 1.f,  0.30901699f, -0.80901699f, -0.80901699f,  0.30901699f};
constexpr float W5I[5] = { 0.f, -0.95105652f, -0.58778525f,  0.58778525f,  0.95105652f};

// ---------------- complex helpers ----------------
__device__ __forceinline__ float2 cmul(float2 a, float2 b){
  return make_float2(a.x*b.x - a.y*b.y, a.x*b.y + a.y*b.x);
}
__device__ __forceinline__ void cmac(float2& d, float2 a, float2 b){
  d.x = fmaf(a.x, b.x, fmaf(-a.y, b.y, d.x));
  d.y = fmaf(a.x, b.y, fmaf( a.y, b.x, d.y));
}

// bf16-packed complex: re in low 16, im in high 16 (round-to-nearest-even)
__device__ __forceinline__ unsigned pk(float2 v){
  unsigned ua = __float_as_uint(v.x), ub = __float_as_uint(v.y);
  ua = (ua + 0x7FFFu + ((ua >> 16) & 1u)) >> 16;
  ub = (ub + 0x7FFFu + ((ub >> 16) & 1u)) >> 16;
  return ua | (ub << 16);
}
__device__ __forceinline__ float2 upk(unsigned v){
  return make_float2(__uint_as_float(v << 16), __uint_as_float(v & 0xFFFF0000u));
}

__device__ __forceinline__ void corners(float gy, float gx, int& y0, int& x0, int& y1, int& x1,
                                        float& w00, float& w01, float& w10, float& w11){
  float y0f = floorf(gy), x0f = floorf(gx);
  float wy = gy - y0f, wx = gx - x0f;
  y0 = (int)y0f; x0 = (int)x0f;
  y1 = min(y0 + 1, HG - 1); x1 = min(x0 + 1, WG - 1);
  w00 = (1.f - wy) * (1.f - wx);
  w01 = (1.f - wy) * wx;
  w10 = wy * (1.f - wx);
  w11 = wy * wx;
}

__device__ __forceinline__ void traj_to_grid(float ty, float tx, float& gy, float& gx){
  gy = fminf(fmaxf((ty / TWO_PI_F + 0.5f) * 320.f, 0.f), 319.f);
  gx = fminf(fmaxf((tx / TWO_PI_F + 0.5f) * 320.f, 0.f), 319.f);
}

// ---------------- in-register 320-pt FFT: one wave per line, N = 5 x 64 ----------------
// (verified rounds 5-16). Lane l stores X[5*br6(l)+r]; un-permuted via LDS seg.
struct FT {
  float2 t1, t2, t3, t4;
  float2 tw0, tw1, tw2, tw3, tw4;
  int br5, lane;
};

__device__ __forceinline__ FT ft_init(){
  FT f; int l = (int)(threadIdx.x & 63); f.lane = l;
  sincosf(-TWO_PI_F * (float)l * (1.0f/320.0f), &f.t1.y, &f.t1.x);
  f.t2 = cmul(f.t1, f.t1); f.t3 = cmul(f.t2, f.t1); f.t4 = cmul(f.t2, f.t2);
  sincosf(-TWO_PI_F * (float)(l & 31) * (1.0f/64.0f), &f.tw0.y, &f.tw0.x);
  sincosf(-TWO_PI_F * (float)(l & 15) * (1.0f/32.0f), &f.tw1.y, &f.tw1.x);
  sincosf(-TWO_PI_F * (float)(l &  7) * (1.0f/16.0f), &f.tw2.y, &f.tw2.x);
  sincosf(-TWO_PI_F * (float)(l &  3) * (1.0f/ 8.0f), &f.tw3.y, &f.tw3.x);
  f.tw4 = (l & 1) ? make_float2(0.f, -1.f) : make_float2(1.f, 0.f);
  int br = ((l&1)<<5) | ((l&2)<<3) | ((l&4)<<1) | ((l&8)>>1) | ((l&16)>>3) | ((l&32)>>5);
  f.br5 = 5 * br;
  return f;
}

template<int H>
__device__ __forceinline__ void bfly(float2& v, float2 tw, int lane){
  float px = __shfl_xor(v.x, H, 64);
  float py = __shfl_xor(v.y, H, 64);
  bool up = (lane & H) != 0;
  float ax = up ? px : v.x, ay = up ? py : v.y;
  float bx = up ? v.x : px, by = up ? v.y : py;
  float dx = ax - bx,  dy = ay - by;
  float mx = fmaf(dx, tw.x, -dy * tw.y);
  float my = fmaf(dx, tw.y,  dy * tw.x);
  v.x = up ? mx : (ax + bx);
  v.y = up ? my : (ay + by);
}

__device__ __forceinline__ void fft320w(const float2 a[5], const FT& f, float2* __restrict__ seg){
  float2 z[5];
  #pragma unroll
  for (int r = 0; r < 5; r++){
    float2 acc = a[0];
    #pragma unroll
    for (int q = 1; q < 5; q++){
      const int j = (q * r) % 5;
      cmac(acc, a[q], make_float2(W5R[j], W5I[j]));
    }
    z[r] = acc;
  }
  z[1] = cmul(z[1], f.t1); z[2] = cmul(z[2], f.t2);
  z[3] = cmul(z[3], f.t3); z[4] = cmul(z[4], f.t4);
  #pragma unroll
  for (int r = 0; r < 5; r++){
    float2 v = z[r];
    bfly<32>(v, f.tw0, f.lane);
    bfly<16>(v, f.tw1, f.lane);
    bfly< 8>(v, f.tw2, f.lane);
    bfly< 4>(v, f.tw3, f.lane);
    bfly< 2>(v, f.tw4, f.lane);
    {
      float px = __shfl_xor(v.x, 1, 64);
      float py = __shfl_xor(v.y, 1, 64);
      bool up = (f.lane & 1) != 0;
      float ax = up ? px : v.x, ay = up ? py : v.y;
      float bx = up ? v.x : px, by = up ? v.y : py;
      v.x = up ? (ax - bx) : (ax + bx);
      v.y = up ? (ay - by) : (ay + by);
    }
    seg[f.br5 + r] = v;
  }
}

// same, but stores bf16-packed into an LDS unsigned array
__device__ __forceinline__ void fft320w_pk(const float2 a[5], const FT& f, unsigned* __restrict__ seg){
  float2 z[5];
  #pragma unroll
  for (int r = 0; r < 5; r++){
    float2 acc = a[0];
    #pragma unroll
    for (int q = 1; q < 5; q++){
      const int j = (q * r) % 5;
      cmac(acc, a[q], make_float2(W5R[j], W5I[j]));
    }
    z[r] = acc;
  }
  z[1] = cmul(z[1], f.t1); z[2] = cmul(z[2], f.t2);
  z[3] = cmul(z[3], f.t3); z[4] = cmul(z[4], f.t4);
  #pragma unroll
  for (int r = 0; r < 5; r++){
    float2 v = z[r];
    bfly<32>(v, f.tw0, f.lane);
    bfly<16>(v, f.tw1, f.lane);
    bfly< 8>(v, f.tw2, f.lane);
    bfly< 4>(v, f.tw3, f.lane);
    bfly< 2>(v, f.tw4, f.lane);
    {
      float px = __shfl_xor(v.x, 1, 64);
      float py = __shfl_xor(v.y, 1, 64);
      bool up = (f.lane & 1) != 0;
      float ax = up ? px : v.x, ay = up ? py : v.y;
      float bx = up ? v.x : px, by = up ? v.y : py;
      v.x = up ? (ax - bx) : (ax + bx);
      v.y = up ? (ay - by) : (ay + by);
    }
    seg[f.br5 + r] = pk(v);
  }
}

// ---------------- k-point x-sorting (once per call; traj constant across iterations) --------
__global__ __launch_bounds__(256) void k_khist(const float* __restrict__ traj, unsigned* __restrict__ xhist){
  int gid = blockIdx.x * 256 + threadIdx.x;
  if (gid >= PH * NKP) return;
  int p = gid >> 12, k = gid & (NKP - 1);
  float gy, gx;
  traj_to_grid(traj[(p * 2 + 0) * NKP + k], traj[(p * 2 + 1) * NKP + k], gy, gx);
  atomicAdd(&xhist[p * WG + (int)floorf(gx)], 1u);
}

__global__ void k_kscan(const unsigned* __restrict__ xhist, unsigned* __restrict__ xcur,
                        unsigned* __restrict__ xbnd){
  int p = threadIdx.x;
  if (p < PH){
    unsigned acc = 0;
    for (int b = 0; b < WG; b++){ xcur[p * WG + b] = acc; xbnd[p * (WG + 1) + b] = acc; acc += xhist[p * WG + b]; }
    xbnd[p * (WG + 1) + WG] = acc;
  }
}

__global__ __launch_bounds__(256) void k_kperm(const float* __restrict__ traj, unsigned* __restrict__ xcur,
                                               float4* __restrict__ permx){
  int gid = blockIdx.x * 256 + threadIdx.x;
  if (gid >= PH * NKP) return;
  int p = gid >> 12, k = gid & (NKP - 1);
  float gy, gx;
  traj_to_grid(traj[(p * 2 + 0) * NKP + k], traj[(p * 2 + 1) * NKP + k], gy, gx);
  unsigned sx = atomicAdd(&xcur[p * WG + (int)floorf(gx)], 1u);
  permx[p * NKP + sx] = make_float4(__uint_as_float((unsigned)k), gy, gx, 0.f);
}

// ---------------- kernels ----------------
__global__ __launch_bounds__(256) void k_init(const float2* __restrict__ img0, float2* __restrict__ x, int n){
  int i = blockIdx.x * 256 + threadIdx.x;
  if (i < n){
    float2 v = img0[i];
    v.x = isnan(v.x) ? 0.f : fminf(fmaxf(v.x, -3.4028235e38f), 3.4028235e38f);
    v.y = isnan(v.y) ? 0.f : fminf(fmaxf(v.y, -3.4028235e38f), 3.4028235e38f);
    x[i] = v;
  }
}

// fused: warped = bilinear-warp(x, mvf); gtv = conj(TV-grad(x)); also zeroes dmax/fbcnt
__global__ __launch_bounds__(256) void k_warp_tv(const float2* __restrict__ x, const float* __restrict__ mvf,
                                                 float2* __restrict__ warped, float2* __restrict__ gtv,
                                                 unsigned int* __restrict__ dmax, unsigned int* __restrict__ fbcnt){
  if (blockIdx.x == 0 && threadIdx.x == 0){ *dmax = 0u; *fbcnt = 0u; }
  int gid = blockIdx.x * 256 + threadIdx.x;          // over PH*ZE*HW2
  int hw = gid % HW2;
  int pz = gid / HW2;
  int zz = pz % ZE, p = pz / ZE, z = zz + 1;
  int h = hw / WG, w = hw - h * WG;
  const float* mv = mvf + ((size_t)(p * 2 + 0) * ZT + z) * HW2;
  float fy = mv[hw];
  float fx = mv[(size_t)ZT * HW2 + hw];
  float gy = fminf(fmaxf((float)h + fy, 0.f), 319.f);
  float gx = fminf(fmaxf((float)w + fx, 0.f), 319.f);
  int y0, x0, y1, x1; float w00, w01, w10, w11;
  corners(gy, gx, y0, x0, y1, x1, w00, w01, w10, w11);
  const float2* xs = x + (size_t)(p * ZT + z) * HW2;
  float2 v00 = xs[y0 * WG + x0], v01 = xs[y0 * WG + x1];
  float2 v10 = xs[y1 * WG + x0], v11 = xs[y1 * WG + x1];
  float2 o;
  o.x = v00.x * w00 + v01.x * w01 + v10.x * w10 + v11.x * w11;
  o.y = v00.y * w00 + v01.y * w01 + v10.y * w10 + v11.y * w11;
  warped[gid] = o;
  // TV gradient
  float2 xc = xs[hw];
  float tre = 0.f, tim = 0.f;
  if (h > 0){
    float2 n = xs[hw - WG];
    float dr = xc.x - n.x, di = xc.y - n.y;
    float r = sqrtf(dr * dr + di * di + 1e-8f);
    tre += dr / r; tim += di / r;
  }
  if (h < HG - 1){
    float2 n = xs[hw + WG];
    float dr = n.x - xc.x, di = n.y - xc.y;
    float r = sqrtf(dr * dr + di * di + 1e-8f);
    tre -= dr / r; tim -= di / r;
  }
  if (w > 0){
    float2 n = xs[hw - 1];
    float dr = xc.x - n.x, di = xc.y - n.y;
    float r = sqrtf(dr * dr + di * di + 1e-8f);
    tre += dr / r; tim += di / r;
  }
  if (w < WG - 1){
    float2 n = xs[hw + 1];
    float dr = n.x - xc.x, di = n.y - xc.y;
    float r = sqrtf(dr * dr + di * di + 1e-8f);
    tre -= dr / r; tim -= di / r;
  }
  gtv[gid] = make_float2(tre, -tim);
}

// row FFT forward: 16 rows of one slice per block (2 per wave, ILP-2 paired FFTs);
// output TRANSPOSED + bf16-packed: FT_[sl][w][h], 4 B per complex.
__global__ __launch_bounds__(512) void k_fft_row_fwd(const float2* __restrict__ warped, const float2* __restrict__ csm,
                                                     unsigned* __restrict__ FT_, int p0){
  __shared__ float2 seg[16 * LSTR];   // 41,088 B
  FT f = ft_init();
  int wid = threadIdx.x >> 6, l = f.lane;
  int hg = blockIdx.x % 20; int sl = blockIdx.x / 20;      // sl = (pp*CHN + c)*ZE + zz
  int zz = sl % ZE; int s2 = sl / ZE; int c = s2 % CHN; int pp = s2 / CHN;
  int p = p0 + pp; int z = zz + 1;
  int h0 = hg * 16 + wid * 2;                              // rows h0, h0+1
  const float2* wr0 = warped + ((size_t)(p * ZE + zz)) * HW2 + (size_t)h0 * WG;
  const float2* cs0 = csm + ((size_t)(c * ZT + z)) * HW2 + (size_t)h0 * WG;
  float sgn0 = ((h0 + l) & 1) ? -1.f : 1.f;
  float2 a0[5], a1[5];
  #pragma unroll
  for (int q = 0; q < 5; q++){
    float2 v0 = cmul(wr0[64 * q + l], cs0[64 * q + l]);
    float2 v1 = cmul(wr0[WG + 64 * q + l], cs0[WG + 64 * q + l]);
    a0[q] = make_float2(v0.x * sgn0, v0.y * sgn0);
    a1[q] = make_float2(-v1.x * sgn0, -v1.y * sgn0);       // parity flips at h0+1
  }
  fft320w(a0, f, seg + (wid * 2) * LSTR);
  fft320w(a1, f, seg + (wid * 2 + 1) * LSTR);
  __syncthreads();
  unsigned* out = FT_ + (size_t)sl * HW2 + hg * 16;        // + w*HG later
  for (int i = threadIdx.x; i < 16 * WG; i += 512){
    int w = i >> 4; int hh = i & 15;
    out[(size_t)w * HG + hh] = pk(seg[hh * LSTR + w]);
  }
}

// fused forward: per block, TWO adjacent slices x (8 owned + 1 overlap) columns.
// FFT pairs give ILP-2 across shuffle chains; spectrum bf16-packed in LDS (23.1 KB).
__global__ __launch_bounds__(256) void k_fft_col_sample(const unsigned* __restrict__ FT_, const float4* __restrict__ permx,
                                                        const unsigned* __restrict__ xbnd, float2* __restrict__ est,
                                                        unsigned int* __restrict__ dmax, int p0){
  __shared__ unsigned seg[2][9 * LSTR];   // 23,112 B (bf16-packed spectrum)
  FT f = ft_init();
  int tid = threadIdx.x; int wid = tid >> 6, l = f.lane;
  int cg = blockIdx.x % 40; int pr = blockIdx.x / 40;       // slice pair (shares pp,c)
  int sl0 = pr * 2;
  int s2 = sl0 / ZE; int pp = s2 / CHN;
  int p = p0 + pp;
  int cbase = cg * 8;
  const int ncol = (cbase + 8 <= WG - 1) ? 9 : 8;
  const unsigned* Fs0 = FT_ + (size_t)sl0 * HW2 + (size_t)cbase * HG;
  const unsigned* Fs1 = Fs0 + HW2;
  unsigned raw0[3][5], raw1[3][5];
  #pragma unroll
  for (int cc = 0; cc < 3; cc++){
    int col = cc * 4 + wid;
    if (col < 9){
      int colc = min(col, ncol - 1);
      const unsigned* s0 = Fs0 + (size_t)colc * HG;
      const unsigned* s1 = Fs1 + (size_t)colc * HG;
      #pragma unroll
      for (int q = 0; q < 5; q++){ raw0[cc][q] = s0[64 * q + l]; raw1[cc][q] = s1[64 * q + l]; }
    }
  }
  #pragma unroll
  for (int cc = 0; cc < 3; cc++){
    int col = cc * 4 + wid;
    if (col < 9){
      int colc = min(col, ncol - 1);
      float2 a0[5], a1[5];
      #pragma unroll
      for (int q = 0; q < 5; q++){ a0[q] = upk(raw0[cc][q]); a1[q] = upk(raw1[cc][q]); }
      fft320w_pk(a0, f, seg[0] + colc * LSTR);
      fft320w_pk(a1, f, seg[1] + colc * LSTR);
    }
  }
  __syncthreads();
  int lo = (int)xbnd[p * (WG + 1) + cbase];
  int hi = (int)xbnd[p * (WG + 1) + min(cbase + 8, WG)];
  float2* eb0 = est + ((size_t)(p0 * CHN * ZE) + sl0) * NKP;
  float2* eb1 = eb0 + NKP;
  const float4* px = permx + p * NKP;
  float md2 = 0.f;
  for (int j = lo + tid; j < hi; j += 256){
    float4 e4 = px[j];
    int y0, x0, y1, x1; float w00, w01, w10, w11;
    corners(e4.y, e4.z, y0, x0, y1, x1, w00, w01, w10, w11);
    int lc0 = x0 - cbase, lc1 = x1 - cbase;
    {
      float2 v00 = upk(seg[0][lc0 * LSTR + y0]), v01 = upk(seg[0][lc1 * LSTR + y0]);
      float2 v10 = upk(seg[0][lc0 * LSTR + y1]), v11 = upk(seg[0][lc1 * LSTR + y1]);
      float2 e;
      e.x = v00.x * w00 + v01.x * w01 + v10.x * w10 + v11.x * w11;
      e.y = v00.y * w00 + v01.y * w01 + v10.y * w10 + v11.y * w11;
      eb0[j] = e;
      md2 = fmaxf(md2, e.x * e.x + e.y * e.y);
    }
    {
      float2 v00 = upk(seg[1][lc0 * LSTR + y0]), v01 = upk(seg[1][lc1 * LSTR + y0]);
      float2 v10 = upk(seg[1][lc0 * LSTR + y1]), v11 = upk(seg[1][lc1 * LSTR + y1]);
      float2 e;
      e.x = v00.x * w00 + v01.x * w01 + v10.x * w10 + v11.x * w11;
      e.y = v00.y * w00 + v01.y * w01 + v10.y * w10 + v11.y * w11;
      eb1[j] = e;
      md2 = fmaxf(md2, e.x * e.x + e.y * e.y);
    }
  }
  for (int off = 32; off > 0; off >>= 1) md2 = fmaxf(md2, __shfl_down(md2, off, 64));
  if ((tid & 63) == 0 && md2 > 0.f) atomicMax(dmax, __float_as_uint(md2));
}

// backward: fused { weights + zero tile + x-bucketed corner scatter (LDS atomics) +
// per-wave column DFT^T with ILP-2 paired columns }. F written NORMAL layout, bf16-packed.
__global__ __launch_bounds__(256) void k_fft_col_scatter(const float2* __restrict__ est, const float2* __restrict__ kdata,
                                                         const float4* __restrict__ permx,
                                                         const unsigned* __restrict__ xbnd,
                                                         const unsigned int* __restrict__ dmax,
                                                         unsigned* __restrict__ F, int p0){
  __shared__ float2 ld[16 * LSTR];
  FT f = ft_init();
  int tid = threadIdx.x; int wid = tid >> 6, l = f.lane;
  int cg = blockIdx.x % 20; int sl = blockIdx.x / 20;       // local slice
  int zz = sl % ZE; int s2 = sl / ZE; int c = s2 % CHN; int pp = s2 / CHN;
  int p = p0 + pp; int z = zz + 1;
  for (int i = tid; i < 16 * LSTR; i += 256) ld[i] = make_float2(0.f, 0.f);
  __syncthreads();
  float md = sqrtf(__uint_as_float(*dmax));
  int cbase = cg * 16;
  int lo = (cbase > 0) ? (int)xbnd[p * (WG + 1) + cbase - 1] : 0;
  int hi = (int)xbnd[p * (WG + 1) + min(cbase + 16, WG)];
  const float2* Es = est + ((size_t)(p0 * CHN * ZE) + sl) * NKP;
  const float2* kd = kdata + ((size_t)(p * CHN + c) * ZT + z) * NKP;
  const float4* px = permx + p * NKP;
  for (int j = lo + tid; j < hi; j += 256){
    float4 e4 = px[j];
    int k = (int)__float_as_uint(e4.x);
    int y0, x0, y1, x1; float w00, w01, w10, w11;
    corners(e4.y, e4.z, y0, x0, y1, x1, w00, w01, w10, w11);
    float2 e = Es[j];
    float det = sqrtf(e.x * e.x + e.y * e.y);
    float wv = 1.0f / (det / md + EPS_C);
    float sc = wv * wv * INV_N;
    float2 y = kd[k];
    float2 gv = make_float2(sc * (e.x - y.x), -sc * (e.y - y.y));
    int c0 = x0 - cbase, c1 = x1 - cbase;
    if ((unsigned)c0 < 16u){
      atomicAdd(&ld[c0 * LSTR + y0].x, gv.x * w00); atomicAdd(&ld[c0 * LSTR + y0].y, gv.y * w00);
      atomicAdd(&ld[c0 * LSTR + y1].x, gv.x * w10); atomicAdd(&ld[c0 * LSTR + y1].y, gv.y * w10);
    }
    if ((unsigned)c1 < 16u){
      atomicAdd(&ld[c1 * LSTR + y0].x, gv.x * w01); atomicAdd(&ld[c1 * LSTR + y0].y, gv.y * w01);
      atomicAdd(&ld[c1 * LSTR + y1].x, gv.x * w11); atomicAdd(&ld[c1 * LSTR + y1].y, gv.y * w11);
    }
  }
  __syncthreads();
  // 4 columns per wave as 2 ILP-2 pairs (reads of both pair inputs precede writes)
  #pragma unroll
  for (int cc = 0; cc < 2; cc++){
    float2* base0 = ld + (wid * 4 + cc * 2) * LSTR;
    float2* base1 = base0 + LSTR;
    float2 a0[5], a1[5];
    #pragma unroll
    for (int q = 0; q < 5; q++){ a0[q] = base0[64 * q + l]; a1[q] = base1[64 * q + l]; }
    fft320w(a0, f, base0);
    fft320w(a1, f, base1);
  }
  __syncthreads();
  unsigned* Fs = F + (size_t)sl * HW2 + cbase;
  for (int i = tid; i < 5120; i += 256){ int h = i >> 4, col = i & 15; Fs[h * WG + col] = pk(ld[col * LSTR + h]); }
}

// transpose row pass: block = 2 rows of one (pp,zz); 8 coil-waves each FFT the row-pair
// (ILP-2). Epilogue *(-1)^(h+w), *csm, coil sum for both rows.
__global__ __launch_bounds__(512) void k_fft_row_bwd(const unsigned* __restrict__ F, const float2* __restrict__ csm,
                                                     float2* __restrict__ gwarped, int p0){
  __shared__ float2 seg[2][8 * LSTR];   // 41,088 B
  FT f = ft_init();
  int tid = threadIdx.x; int c = tid >> 6, l = f.lane;
  int bid = blockIdx.x;                          // over np*ZE*160
  int h2 = bid % 160; int b2 = bid / 160;
  int zz = b2 % ZE; int pp = b2 / ZE;
  int p = p0 + pp; int z = zz + 1;
  int h0 = h2 * 2;
  const unsigned* Fl = F + ((size_t)((pp * CHN + c) * ZE + zz)) * HW2 + (size_t)h0 * WG;
  float2 a0[5], a1[5];
  #pragma unroll
  for (int q = 0; q < 5; q++){ a0[q] = upk(Fl[64 * q + l]); a1[q] = upk(Fl[WG + 64 * q + l]); }
  fft320w(a0, f, seg[0] + c * LSTR);
  fft320w(a1, f, seg[1] + c * LSTR);
  __syncthreads();
  for (int i = tid; i < 2 * WG; i += 512){
    int hh = i / WG; int w = i - hh * WG;
    int h = h0 + hh;
    float2 acc = make_float2(0.f, 0.f);
    #pragma unroll
    for (int cc = 0; cc < 8; cc++){
      cmac(acc, seg[hh][cc * LSTR + w], csm[((size_t)(cc * ZT + z)) * HW2 + (size_t)h * WG + w]);
    }
    float sg = ((h + w) & 1) ? -1.f : 1.f;
    gwarped[((size_t)(p * ZE + zz)) * HW2 + (size_t)h * WG + w] = make_float2(acc.x * sg, acc.y * sg);
  }
}

// ---------------- gather-tiled warp adjoint + fused gradient update ----------------
#define TRG 8
#define HAG 8
__global__ __launch_bounds__(512) void k_warpadj_update(const float2* __restrict__ gw, const float* __restrict__ mvf,
                                                        const float2* __restrict__ gtv, const float* __restrict__ stdp,
                                                        float2* __restrict__ x,
                                                        uint4* __restrict__ fb, unsigned int* __restrict__ fbcnt){
  __shared__ float lt[TRG * WG * 2];   // 20480 B
  int tid = threadIdx.x;
  int bid = blockIdx.x;                    // pz*40 + tile
  int tile = bid % 40; int pz = bid / 40;
  int zz = pz % ZE, p = pz / ZE, z = zz + 1;
  int R = tile * TRG;
  for (int i = tid; i < TRG * WG * 2; i += 512) lt[i] = 0.f;
  __syncthreads();
  const float* mvy = mvf + ((size_t)(p * 2 + 0) * ZT + z) * HW2;
  const float* mvx = mvy + (size_t)ZT * HW2;
  const float2* g = gw + (size_t)pz * HW2;
  const size_t xbase = (size_t)(p * ZT + z) * HW2;
  int wlo = max(R - HAG, 0), whi = min(R + TRG + HAG, HG);
  int npx = (whi - wlo) * WG;
  int base0 = wlo * WG;
  int i = tid;
  float fy = 0.f, fx = 0.f; float2 gv = make_float2(0.f, 0.f);
  if (i < npx){ fy = mvy[base0 + i]; fx = mvx[base0 + i]; gv = g[base0 + i]; }
  while (i < npx){
    int inx = i + 512;
    float fy2 = 0.f, fx2 = 0.f; float2 gv2 = make_float2(0.f, 0.f);
    if (inx < npx){ fy2 = mvy[base0 + inx]; fx2 = mvx[base0 + inx]; gv2 = g[base0 + inx]; }
    int hh = i / WG; int w = i - hh * WG;
    int h = wlo + hh;
    float gy = fminf(fmaxf((float)h + fy, 0.f), 319.f);
    float gx = fminf(fmaxf((float)w + fx, 0.f), 319.f);
    int y0, x0, y1, x1; float w00, w01, w10, w11;
    corners(gy, gx, y0, x0, y1, x1, w00, w01, w10, w11);
    bool owner = (h >= R) && (h < R + TRG);
    #define PROC(Y, XC, WT) { \
      int ry = (Y) - R; \
      if ((unsigned)ry < (unsigned)TRG){ \
        atomicAdd(&lt[(ry * WG + (XC)) * 2 + 0], gv.x * (WT)); \
        atomicAdd(&lt[(ry * WG + (XC)) * 2 + 1], gv.y * (WT)); \
      } else if (owner){ \
        int Ry = (Y) & ~(TRG - 1); \
        if (h < Ry - HAG || h >= Ry + TRG + HAG){ \
          unsigned slot = atomicAdd(fbcnt, 1u); \
          if (slot < FBCAP) fb[slot] = make_uint4((unsigned)(xbase + (size_t)(Y) * WG + (XC)), \
                                                  __float_as_uint(gv.x * (WT)), __float_as_uint(gv.y * (WT)), 0u); \
        } \
      } \
    }
    PROC(y0, x0, w00); PROC(y0, x1, w01); PROC(y1, x0, w10); PROC(y1, x1, w11);
    #undef PROC
    i = inx; fy = fy2; fx = fx2; gv = gv2;
  }
  __syncthreads();
  float s = stdp[0];
  const float2* gt = gtv + (size_t)pz * HW2;
  for (int i2 = tid; i2 < TRG * WG; i2 += 512){
    int yy = i2 / WG; int w = i2 - yy * WG;
    int hw = (R + yy) * WG + w;
    float2 xv = x[xbase + hw];
    float2 tv = gt[hw];
    xv.x -= GAMMA_C * lt[i2 * 2 + 0] + TAU_C * s * tv.x;
    xv.y -= GAMMA_C * lt[i2 * 2 + 1] + TAU_C * s * tv.y;
    x[xbase + hw] = xv;
  }
}

// apply rare out-of-halo contributions: x[idx] -= GAMMA * val
__global__ __launch_bounds__(256) void k_fixup(const uint4* __restrict__ fb, const unsigned int* __restrict__ fbcnt,
                                               float2* __restrict__ x){
  unsigned n = *fbcnt; if (n > FBCAP) n = FBCAP;
  for (unsigned i = blockIdx.x * 256 + threadIdx.x; i < n; i += gridDim.x * 256){
    uint4 e = fb[i];
    atomicAdd(&x[e.x].x, -GAMMA_C * __uint_as_float(e.y));
    atomicAdd(&x[e.x].y, -GAMMA_C * __uint_as_float(e.z));
  }
}

// ---------------- host ----------------
extern "C" void kernel_launch(void* const* d_in, const int* in_sizes, int n_in,
                              void* d_out, int out_size, void* d_ws, size_t ws_size,
                              hipStream_t stream) {
  const float2* kdata = (const float2*)d_in[0];
  const float*  traj  = (const float*) d_in[1];
  const float2* img0  = (const float2*)d_in[2];
  const float*  mvf   = (const float*) d_in[3];
  const float2* csm   = (const float2*)d_in[4];
  const float*  stdp  = (const float*) d_in[5];
  float2* x = (float2*)d_out;

  const size_t F_B  = (size_t)CHN * ZE * HW2 * 4;        // 19,660,800 (bf16-packed complex)
  const size_t W_B  = (size_t)PH * ZE * HW2 * 8;         // 19,660,800
  const size_t E_B  = (size_t)PH * CHN * ZE * NKP * 8;   //  6,291,456
  const size_t FB_B = (size_t)FBCAP * 16;                //  2,097,152
  const size_t P_B  = (size_t)PH * NKP * 16;             //    262,144
  const size_t SORT_B = P_B + 4 * 8192;

  size_t need_big = 4 * F_B + 2 * W_B + E_B + 512 + FB_B + SORT_B;   // ~128 MB
  const int NP = (ws_size >= need_big) ? 4 : 1;

  char* cur = (char*)d_ws;
  unsigned* F    = (unsigned*)cur;  cur += (size_t)NP * F_B;  // fwd: transposed; bwd: normal (bf16 packed)
  float2* warped = (float2*)cur;  cur += W_B;                 // also holds gwarped
  float2* est    = (float2*)cur;  cur += E_B;
  float2* gtvb   = (float2*)cur;  cur += W_B;
  unsigned int* dmax  = (unsigned int*)cur; cur += 128;
  unsigned int* fbcnt = (unsigned int*)cur; cur += 128;
  uint4* fb           = (uint4*)cur;        cur += FB_B;
  float4* permx       = (float4*)cur;       cur += P_B;
  unsigned* xhist     = (unsigned*)cur;     cur += 8192;
  unsigned* xcur      = (unsigned*)cur;     cur += 8192;
  unsigned* xbnd      = (unsigned*)cur;     cur += 8192;

  k_init<<<12800, 256, 0, stream>>>(img0, x, PH * ZT * HW2);
  // build x-sorted k-point list (traj constant across iterations)
  hipMemsetAsync(xhist, 0, 8192, stream);
  k_khist<<<64, 256, 0, stream>>>(traj, xhist);
  k_kscan<<<1, 64, 0, stream>>>(xhist, xcur, xbnd);
  k_kperm<<<64, 256, 0, stream>>>(traj, xcur, permx);

  for (int it = 0; it < 3; it++){
    k_warp_tv<<<9600, 256, 0, stream>>>(x, mvf, warped, gtvb, dmax, fbcnt);
    for (int p0 = 0; p0 < PH; p0 += NP){
      k_fft_row_fwd   <<<NP *  960, 512, 0, stream>>>(warped, csm, F, p0);            // 16 rows/block
      k_fft_col_sample<<<NP *  960, 256, 0, stream>>>(F, permx, xbnd, est, dmax, p0); // 2 slices/block
    }
    for (int p0 = 0; p0 < PH; p0 += NP){
      k_fft_col_scatter<<<NP *  960, 256, 0, stream>>>(est, kdata, permx, xbnd, dmax, F, p0);
      k_fft_row_bwd    <<<NP *  960, 512, 0, stream>>>(F, csm, warped, p0);           // 2 rows/block
    }
    k_warpadj_update<<<960, 512, 0, stream>>>(warped, mvf, gtvb, stdp, x, fb, fbcnt);
    k_fixup<<<16, 256, 0, stream>>>(fb, fbcnt, x);
  }
}

// Round 18
// 1478.283 us; speedup vs baseline: 1.2570x; 1.0258x over previous
//
#include <hip/hip_runtime.h>
#include <math.h>

// ---------------- problem constants ----------------
#define PH   4
#define CHN  8
#define ZT   8
#define ZE   6          // effective z slices: z in [1,7)
#define HG   320
#define WG   320
#define HW2  102400     // 320*320
#define NKP  4096
#define LSTR 321        // LDS line stride (pad +1)
#define FBCAP 131072u   // fallback list capacity (entries)

constexpr float GAMMA_C = 0.1f;
constexpr float TAU_C   = 0.2f;
constexpr float EPS_C   = 0.01f;
constexpr float INV_N   = 1.0f / 786432.0f;   // PH*CHN*ZE*NKP
#define TWO_PI_F 6.28318530717958647692f

// W5^j = e^{-2*pi*i*j/5}
constexpr float W5R[5] = { 1.f,  0.30901699f, -0.80901699f, -0.80901699f,  0.30901699f};
constexpr float W5I[5] = { 0.f, -0.95105652f, -0.58778525f,  0.58778525f,  0.95105652f};

// ---------------- complex helpers ----------------
__device__ __forceinline__ float2 cmul(float2 a, float2 b){
  return make_float2(a.x*b.x - a.y*b.y, a.x*b.y + a.y*b.x);
}
__device__ __forceinline__ void cmac(float2& d, float2 a, float2 b){
  d.x = fmaf(a.x, b.x, fmaf(-a.y, b.y, d.x));
  d.y = fmaf(a.x, b.y, fmaf( a.y, b.x, d.y));
}

// bf16-packed complex: re in low 16, im in high 16 (round-to-nearest-even)
__device__ __forceinline__ unsigned pk(float2 v){
  unsigned ua = __float_as_uint(v.x), ub = __float_as_uint(v.y);
  ua = (ua + 0x7FFFu + ((ua >> 16) & 1u)) >> 16;
  ub = (ub + 0x7FFFu + ((ub >> 16) & 1u)) >> 16;
  return ua | (ub << 16);
}
__device__ __forceinline__ float2 upk(unsigned v){
  return make_float2(__uint_as_float(v << 16), __uint_as_float(v & 0xFFFF0000u));
}

__device__ __forceinline__ void corners(float gy, float gx, int& y0, int& x0, int& y1, int& x1,
                                        float& w00, float& w01, float& w10, float& w11){
  float y0f = floorf(gy), x0f = floorf(gx);
  float wy = gy - y0f, wx = gx - x0f;
  y0 = (int)y0f; x0 = (int)x0f;
  y1 = min(y0 + 1, HG - 1); x1 = min(x0 + 1, WG - 1);
  w00 = (1.f - wy) * (1.f - wx);
  w01 = (1.f - wy) * wx;
  w10 = wy * (1.f - wx);
  w11 = wy * wx;
}

__device__ __forceinline__ void traj_to_grid(float ty, float tx, float& gy, float& gx){
  gy = fminf(fmaxf((ty / TWO_PI_F + 0.5f) * 320.f, 0.f), 319.f);
  gx = fminf(fmaxf((tx / TWO_PI_F + 0.5f) * 320.f, 0.f), 319.f);
}

// ---------------- in-register 320-pt FFT: one wave per line, N = 5 x 64 ----------------
// (verified rounds 5-17). Lane l stores X[5*br6(l)+r]; un-permuted via LDS seg.
struct FT {
  float2 t1, t2, t3, t4;
  float2 tw0, tw1, tw2, tw3, tw4;
  int br5, lane;
};

__device__ __forceinline__ FT ft_init(){
  FT f; int l = (int)(threadIdx.x & 63); f.lane = l;
  sincosf(-TWO_PI_F * (float)l * (1.0f/320.0f), &f.t1.y, &f.t1.x);
  f.t2 = cmul(f.t1, f.t1); f.t3 = cmul(f.t2, f.t1); f.t4 = cmul(f.t2, f.t2);
  sincosf(-TWO_PI_F * (float)(l & 31) * (1.0f/64.0f), &f.tw0.y, &f.tw0.x);
  sincosf(-TWO_PI_F * (float)(l & 15) * (1.0f/32.0f), &f.tw1.y, &f.tw1.x);
  sincosf(-TWO_PI_F * (float)(l &  7) * (1.0f/16.0f), &f.tw2.y, &f.tw2.x);
  sincosf(-TWO_PI_F * (float)(l &  3) * (1.0f/ 8.0f), &f.tw3.y, &f.tw3.x);
  f.tw4 = (l & 1) ? make_float2(0.f, -1.f) : make_float2(1.f, 0.f);
  int br = ((l&1)<<5) | ((l&2)<<3) | ((l&4)<<1) | ((l&8)>>1) | ((l&16)>>3) | ((l&32)>>5);
  f.br5 = 5 * br;
  return f;
}

template<int H>
__device__ __forceinline__ void bfly(float2& v, float2 tw, int lane){
  float px = __shfl_xor(v.x, H, 64);
  float py = __shfl_xor(v.y, H, 64);
  bool up = (lane & H) != 0;
  float ax = up ? px : v.x, ay = up ? py : v.y;
  float bx = up ? v.x : px, by = up ? v.y : py;
  float dx = ax - bx,  dy = ay - by;
  float mx = fmaf(dx, tw.x, -dy * tw.y);
  float my = fmaf(dx, tw.y,  dy * tw.x);
  v.x = up ? mx : (ax + bx);
  v.y = up ? my : (ay + by);
}

__device__ __forceinline__ void fft320w(const float2 a[5], const FT& f, float2* __restrict__ seg){
  float2 z[5];
  #pragma unroll
  for (int r = 0; r < 5; r++){
    float2 acc = a[0];
    #pragma unroll
    for (int q = 1; q < 5; q++){
      const int j = (q * r) % 5;
      cmac(acc, a[q], make_float2(W5R[j], W5I[j]));
    }
    z[r] = acc;
  }
  z[1] = cmul(z[1], f.t1); z[2] = cmul(z[2], f.t2);
  z[3] = cmul(z[3], f.t3); z[4] = cmul(z[4], f.t4);
  #pragma unroll
  for (int r = 0; r < 5; r++){
    float2 v = z[r];
    bfly<32>(v, f.tw0, f.lane);
    bfly<16>(v, f.tw1, f.lane);
    bfly< 8>(v, f.tw2, f.lane);
    bfly< 4>(v, f.tw3, f.lane);
    bfly< 2>(v, f.tw4, f.lane);
    {
      float px = __shfl_xor(v.x, 1, 64);
      float py = __shfl_xor(v.y, 1, 64);
      bool up = (f.lane & 1) != 0;
      float ax = up ? px : v.x, ay = up ? py : v.y;
      float bx = up ? v.x : px, by = up ? v.y : py;
      v.x = up ? (ax - bx) : (ax + bx);
      v.y = up ? (ay - by) : (ay + by);
    }
    seg[f.br5 + r] = v;
  }
}

// same, but stores bf16-packed into an LDS unsigned array
__device__ __forceinline__ void fft320w_pk(const float2 a[5], const FT& f, unsigned* __restrict__ seg){
  float2 z[5];
  #pragma unroll
  for (int r = 0; r < 5; r++){
    float2 acc = a[0];
    #pragma unroll
    for (int q = 1; q < 5; q++){
      const int j = (q * r) % 5;
      cmac(acc, a[q], make_float2(W5R[j], W5I[j]));
    }
    z[r] = acc;
  }
  z[1] = cmul(z[1], f.t1); z[2] = cmul(z[2], f.t2);
  z[3] = cmul(z[3], f.t3); z[4] = cmul(z[4], f.t4);
  #pragma unroll
  for (int r = 0; r < 5; r++){
    float2 v = z[r];
    bfly<32>(v, f.tw0, f.lane);
    bfly<16>(v, f.tw1, f.lane);
    bfly< 8>(v, f.tw2, f.lane);
    bfly< 4>(v, f.tw3, f.lane);
    bfly< 2>(v, f.tw4, f.lane);
    {
      float px = __shfl_xor(v.x, 1, 64);
      float py = __shfl_xor(v.y, 1, 64);
      bool up = (f.lane & 1) != 0;
      float ax = up ? px : v.x, ay = up ? py : v.y;
      float bx = up ? v.x : px, by = up ? v.y : py;
      v.x = up ? (ax - bx) : (ax + bx);
      v.y = up ? (ay - by) : (ay + by);
    }
    seg[f.br5 + r] = pk(v);
  }
}

// ---------------- k-point x-sorting (once per call; traj constant across iterations) --------
__global__ __launch_bounds__(256) void k_khist(const float* __restrict__ traj, unsigned* __restrict__ xhist){
  int gid = blockIdx.x * 256 + threadIdx.x;
  if (gid >= PH * NKP) return;
  int p = gid >> 12, k = gid & (NKP - 1);
  float gy, gx;
  traj_to_grid(traj[(p * 2 + 0) * NKP + k], traj[(p * 2 + 1) * NKP + k], gy, gx);
  atomicAdd(&xhist[p * WG + (int)floorf(gx)], 1u);
}

__global__ void k_kscan(const unsigned* __restrict__ xhist, unsigned* __restrict__ xcur,
                        unsigned* __restrict__ xbnd){
  int p = threadIdx.x;
  if (p < PH){
    unsigned acc = 0;
    for (int b = 0; b < WG; b++){ xcur[p * WG + b] = acc; xbnd[p * (WG + 1) + b] = acc; acc += xhist[p * WG + b]; }
    xbnd[p * (WG + 1) + WG] = acc;
  }
}

__global__ __launch_bounds__(256) void k_kperm(const float* __restrict__ traj, unsigned* __restrict__ xcur,
                                               float4* __restrict__ permx){
  int gid = blockIdx.x * 256 + threadIdx.x;
  if (gid >= PH * NKP) return;
  int p = gid >> 12, k = gid & (NKP - 1);
  float gy, gx;
  traj_to_grid(traj[(p * 2 + 0) * NKP + k], traj[(p * 2 + 1) * NKP + k], gy, gx);
  unsigned sx = atomicAdd(&xcur[p * WG + (int)floorf(gx)], 1u);
  permx[p * NKP + sx] = make_float4(__uint_as_float((unsigned)k), gy, gx, 0.f);
}

// pack csm to bf16 once per call
__global__ __launch_bounds__(256) void k_pack_csm(const float2* __restrict__ csm, unsigned* __restrict__ csmb, int n){
  int i = blockIdx.x * 256 + threadIdx.x;
  if (i < n) csmb[i] = pk(csm[i]);
}

// ---------------- kernels ----------------
__global__ __launch_bounds__(256) void k_init(const float2* __restrict__ img0, float2* __restrict__ x, int n){
  int i = blockIdx.x * 256 + threadIdx.x;
  if (i < n){
    float2 v = img0[i];
    v.x = isnan(v.x) ? 0.f : fminf(fmaxf(v.x, -3.4028235e38f), 3.4028235e38f);
    v.y = isnan(v.y) ? 0.f : fminf(fmaxf(v.y, -3.4028235e38f), 3.4028235e38f);
    x[i] = v;
  }
}

// fused: warped(bf16) = bilinear-warp(x, mvf); gtv(bf16) = conj(TV-grad(x)); zeroes dmax/fbcnt
__global__ __launch_bounds__(256) void k_warp_tv(const float2* __restrict__ x, const float* __restrict__ mvf,
                                                 unsigned* __restrict__ warped, unsigned* __restrict__ gtv,
                                                 unsigned int* __restrict__ dmax, unsigned int* __restrict__ fbcnt){
  if (blockIdx.x == 0 && threadIdx.x == 0){ *dmax = 0u; *fbcnt = 0u; }
  int gid = blockIdx.x * 256 + threadIdx.x;          // over PH*ZE*HW2
  int hw = gid % HW2;
  int pz = gid / HW2;
  int zz = pz % ZE, p = pz / ZE, z = zz + 1;
  int h = hw / WG, w = hw - h * WG;
  const float* mv = mvf + ((size_t)(p * 2 + 0) * ZT + z) * HW2;
  float fy = mv[hw];
  float fx = mv[(size_t)ZT * HW2 + hw];
  float gy = fminf(fmaxf((float)h + fy, 0.f), 319.f);
  float gx = fminf(fmaxf((float)w + fx, 0.f), 319.f);
  int y0, x0, y1, x1; float w00, w01, w10, w11;
  corners(gy, gx, y0, x0, y1, x1, w00, w01, w10, w11);
  const float2* xs = x + (size_t)(p * ZT + z) * HW2;
  float2 v00 = xs[y0 * WG + x0], v01 = xs[y0 * WG + x1];
  float2 v10 = xs[y1 * WG + x0], v11 = xs[y1 * WG + x1];
  float2 o;
  o.x = v00.x * w00 + v01.x * w01 + v10.x * w10 + v11.x * w11;
  o.y = v00.y * w00 + v01.y * w01 + v10.y * w10 + v11.y * w11;
  warped[gid] = pk(o);
  // TV gradient
  float2 xc = xs[hw];
  float tre = 0.f, tim = 0.f;
  if (h > 0){
    float2 n = xs[hw - WG];
    float dr = xc.x - n.x, di = xc.y - n.y;
    float r = sqrtf(dr * dr + di * di + 1e-8f);
    tre += dr / r; tim += di / r;
  }
  if (h < HG - 1){
    float2 n = xs[hw + WG];
    float dr = n.x - xc.x, di = n.y - xc.y;
    float r = sqrtf(dr * dr + di * di + 1e-8f);
    tre -= dr / r; tim -= di / r;
  }
  if (w > 0){
    float2 n = xs[hw - 1];
    float dr = xc.x - n.x, di = xc.y - n.y;
    float r = sqrtf(dr * dr + di * di + 1e-8f);
    tre += dr / r; tim += di / r;
  }
  if (w < WG - 1){
    float2 n = xs[hw + 1];
    float dr = n.x - xc.x, di = n.y - xc.y;
    float r = sqrtf(dr * dr + di * di + 1e-8f);
    tre -= dr / r; tim -= di / r;
  }
  gtv[gid] = pk(make_float2(tre, -tim));
}

// row FFT forward: 16 rows of one slice per block (2 per wave, ILP-2 paired FFTs);
// inputs warped/csm bf16; output TRANSPOSED + bf16-packed FT_[sl][w][h].
__global__ __launch_bounds__(512) void k_fft_row_fwd(const unsigned* __restrict__ warped, const unsigned* __restrict__ csmb,
                                                     unsigned* __restrict__ FT_, int p0){
  __shared__ float2 seg[16 * LSTR];   // 41,088 B
  FT f = ft_init();
  int wid = threadIdx.x >> 6, l = f.lane;
  int hg = blockIdx.x % 20; int sl = blockIdx.x / 20;      // sl = (pp*CHN + c)*ZE + zz
  int zz = sl % ZE; int s2 = sl / ZE; int c = s2 % CHN; int pp = s2 / CHN;
  int p = p0 + pp; int z = zz + 1;
  int h0 = hg * 16 + wid * 2;                              // rows h0, h0+1
  const unsigned* wr0 = warped + ((size_t)(p * ZE + zz)) * HW2 + (size_t)h0 * WG;
  const unsigned* cs0 = csmb + ((size_t)(c * ZT + z)) * HW2 + (size_t)h0 * WG;
  float sgn0 = ((h0 + l) & 1) ? -1.f : 1.f;
  float2 a0[5], a1[5];
  #pragma unroll
  for (int q = 0; q < 5; q++){
    float2 v0 = cmul(upk(wr0[64 * q + l]), upk(cs0[64 * q + l]));
    float2 v1 = cmul(upk(wr0[WG + 64 * q + l]), upk(cs0[WG + 64 * q + l]));
    a0[q] = make_float2(v0.x * sgn0, v0.y * sgn0);
    a1[q] = make_float2(-v1.x * sgn0, -v1.y * sgn0);       // parity flips at h0+1
  }
  fft320w(a0, f, seg + (wid * 2) * LSTR);
  fft320w(a1, f, seg + (wid * 2 + 1) * LSTR);
  __syncthreads();
  unsigned* out = FT_ + (size_t)sl * HW2 + hg * 16;        // + w*HG later
  for (int i = threadIdx.x; i < 16 * WG; i += 512){
    int w = i >> 4; int hh = i & 15;
    out[(size_t)w * HG + hh] = pk(seg[hh * LSTR + w]);
  }
}

// fused forward: per block, TWO adjacent slices x (8 owned + 1 overlap) columns.
// FFT pairs give ILP-2; spectrum bf16-packed in LDS (23.1 KB).
__global__ __launch_bounds__(256) void k_fft_col_sample(const unsigned* __restrict__ FT_, const float4* __restrict__ permx,
                                                        const unsigned* __restrict__ xbnd, float2* __restrict__ est,
                                                        unsigned int* __restrict__ dmax, int p0){
  __shared__ unsigned seg[2][9 * LSTR];   // 23,112 B
  FT f = ft_init();
  int tid = threadIdx.x; int wid = tid >> 6, l = f.lane;
  int cg = blockIdx.x % 40; int pr = blockIdx.x / 40;       // slice pair (shares pp,c)
  int sl0 = pr * 2;
  int s2 = sl0 / ZE; int pp = s2 / CHN;
  int p = p0 + pp;
  int cbase = cg * 8;
  const int ncol = (cbase + 8 <= WG - 1) ? 9 : 8;
  const unsigned* Fs0 = FT_ + (size_t)sl0 * HW2 + (size_t)cbase * HG;
  const unsigned* Fs1 = Fs0 + HW2;
  unsigned raw0[3][5], raw1[3][5];
  #pragma unroll
  for (int cc = 0; cc < 3; cc++){
    int col = cc * 4 + wid;
    if (col < 9){
      int colc = min(col, ncol - 1);
      const unsigned* s0 = Fs0 + (size_t)colc * HG;
      const unsigned* s1 = Fs1 + (size_t)colc * HG;
      #pragma unroll
      for (int q = 0; q < 5; q++){ raw0[cc][q] = s0[64 * q + l]; raw1[cc][q] = s1[64 * q + l]; }
    }
  }
  #pragma unroll
  for (int cc = 0; cc < 3; cc++){
    int col = cc * 4 + wid;
    if (col < 9){
      int colc = min(col, ncol - 1);
      float2 a0[5], a1[5];
      #pragma unroll
      for (int q = 0; q < 5; q++){ a0[q] = upk(raw0[cc][q]); a1[q] = upk(raw1[cc][q]); }
      fft320w_pk(a0, f, seg[0] + colc * LSTR);
      fft320w_pk(a1, f, seg[1] + colc * LSTR);
    }
  }
  __syncthreads();
  int lo = (int)xbnd[p * (WG + 1) + cbase];
  int hi = (int)xbnd[p * (WG + 1) + min(cbase + 8, WG)];
  float2* eb0 = est + ((size_t)(p0 * CHN * ZE) + sl0) * NKP;
  float2* eb1 = eb0 + NKP;
  const float4* px = permx + p * NKP;
  float md2 = 0.f;
  for (int j = lo + tid; j < hi; j += 256){
    float4 e4 = px[j];
    int y0, x0, y1, x1; float w00, w01, w10, w11;
    corners(e4.y, e4.z, y0, x0, y1, x1, w00, w01, w10, w11);
    int lc0 = x0 - cbase, lc1 = x1 - cbase;
    {
      float2 v00 = upk(seg[0][lc0 * LSTR + y0]), v01 = upk(seg[0][lc1 * LSTR + y0]);
      float2 v10 = upk(seg[0][lc0 * LSTR + y1]), v11 = upk(seg[0][lc1 * LSTR + y1]);
      float2 e;
      e.x = v00.x * w00 + v01.x * w01 + v10.x * w10 + v11.x * w11;
      e.y = v00.y * w00 + v01.y * w01 + v10.y * w10 + v11.y * w11;
      eb0[j] = e;
      md2 = fmaxf(md2, e.x * e.x + e.y * e.y);
    }
    {
      float2 v00 = upk(seg[1][lc0 * LSTR + y0]), v01 = upk(seg[1][lc1 * LSTR + y0]);
      float2 v10 = upk(seg[1][lc0 * LSTR + y1]), v11 = upk(seg[1][lc1 * LSTR + y1]);
      float2 e;
      e.x = v00.x * w00 + v01.x * w01 + v10.x * w10 + v11.x * w11;
      e.y = v00.y * w00 + v01.y * w01 + v10.y * w10 + v11.y * w11;
      eb1[j] = e;
      md2 = fmaxf(md2, e.x * e.x + e.y * e.y);
    }
  }
  for (int off = 32; off > 0; off >>= 1) md2 = fmaxf(md2, __shfl_down(md2, off, 64));
  if ((tid & 63) == 0 && md2 > 0.f) atomicMax(dmax, __float_as_uint(md2));
}

// backward: fused { weights + zero tile + x-bucketed corner scatter (LDS atomics) +
// per-wave column DFT^T with ILP-2 paired columns }. F written NORMAL layout, bf16-packed.
__global__ __launch_bounds__(256) void k_fft_col_scatter(const float2* __restrict__ est, const float2* __restrict__ kdata,
                                                         const float4* __restrict__ permx,
                                                         const unsigned* __restrict__ xbnd,
                                                         const unsigned int* __restrict__ dmax,
                                                         unsigned* __restrict__ F, int p0){
  __shared__ float2 ld[16 * LSTR];
  FT f = ft_init();
  int tid = threadIdx.x; int wid = tid >> 6, l = f.lane;
  int cg = blockIdx.x % 20; int sl = blockIdx.x / 20;       // local slice
  int zz = sl % ZE; int s2 = sl / ZE; int c = s2 % CHN; int pp = s2 / CHN;
  int p = p0 + pp; int z = zz + 1;
  for (int i = tid; i < 16 * LSTR; i += 256) ld[i] = make_float2(0.f, 0.f);
  __syncthreads();
  float md = sqrtf(__uint_as_float(*dmax));
  int cbase = cg * 16;
  int lo = (cbase > 0) ? (int)xbnd[p * (WG + 1) + cbase - 1] : 0;
  int hi = (int)xbnd[p * (WG + 1) + min(cbase + 16, WG)];
  const float2* Es = est + ((size_t)(p0 * CHN * ZE) + sl) * NKP;
  const float2* kd = kdata + ((size_t)(p * CHN + c) * ZT + z) * NKP;
  const float4* px = permx + p * NKP;
  for (int j = lo + tid; j < hi; j += 256){
    float4 e4 = px[j];
    int k = (int)__float_as_uint(e4.x);
    int y0, x0, y1, x1; float w00, w01, w10, w11;
    corners(e4.y, e4.z, y0, x0, y1, x1, w00, w01, w10, w11);
    float2 e = Es[j];
    float det = sqrtf(e.x * e.x + e.y * e.y);
    float wv = 1.0f / (det / md + EPS_C);
    float sc = wv * wv * INV_N;
    float2 y = kd[k];
    float2 gv = make_float2(sc * (e.x - y.x), -sc * (e.y - y.y));
    int c0 = x0 - cbase, c1 = x1 - cbase;
    if ((unsigned)c0 < 16u){
      atomicAdd(&ld[c0 * LSTR + y0].x, gv.x * w00); atomicAdd(&ld[c0 * LSTR + y0].y, gv.y * w00);
      atomicAdd(&ld[c0 * LSTR + y1].x, gv.x * w10); atomicAdd(&ld[c0 * LSTR + y1].y, gv.y * w10);
    }
    if ((unsigned)c1 < 16u){
      atomicAdd(&ld[c1 * LSTR + y0].x, gv.x * w01); atomicAdd(&ld[c1 * LSTR + y0].y, gv.y * w01);
      atomicAdd(&ld[c1 * LSTR + y1].x, gv.x * w11); atomicAdd(&ld[c1 * LSTR + y1].y, gv.y * w11);
    }
  }
  __syncthreads();
  #pragma unroll
  for (int cc = 0; cc < 2; cc++){
    float2* base0 = ld + (wid * 4 + cc * 2) * LSTR;
    float2* base1 = base0 + LSTR;
    float2 a0[5], a1[5];
    #pragma unroll
    for (int q = 0; q < 5; q++){ a0[q] = base0[64 * q + l]; a1[q] = base1[64 * q + l]; }
    fft320w(a0, f, base0);
    fft320w(a1, f, base1);
  }
  __syncthreads();
  unsigned* Fs = F + (size_t)sl * HW2 + cbase;
  for (int i = tid; i < 5120; i += 256){ int h = i >> 4, col = i & 15; Fs[h * WG + col] = pk(ld[col * LSTR + h]); }
}

// transpose row pass: block = 2 rows of one (pp,zz); 8 coil-waves each FFT the row-pair
// (ILP-2). Epilogue *(-1)^(h+w), *csm(bf16), coil sum; output gwarped bf16-packed.
__global__ __launch_bounds__(512) void k_fft_row_bwd(const unsigned* __restrict__ F, const unsigned* __restrict__ csmb,
                                                     unsigned* __restrict__ gwarped, int p0){
  __shared__ float2 seg[2][8 * LSTR];   // 41,088 B
  FT f = ft_init();
  int tid = threadIdx.x; int c = tid >> 6, l = f.lane;
  int bid = blockIdx.x;                          // over np*ZE*160
  int h2 = bid % 160; int b2 = bid / 160;
  int zz = b2 % ZE; int pp = b2 / ZE;
  int p = p0 + pp; int z = zz + 1;
  int h0 = h2 * 2;
  const unsigned* Fl = F + ((size_t)((pp * CHN + c) * ZE + zz)) * HW2 + (size_t)h0 * WG;
  float2 a0[5], a1[5];
  #pragma unroll
  for (int q = 0; q < 5; q++){ a0[q] = upk(Fl[64 * q + l]); a1[q] = upk(Fl[WG + 64 * q + l]); }
  fft320w(a0, f, seg[0] + c * LSTR);
  fft320w(a1, f, seg[1] + c * LSTR);
  __syncthreads();
  for (int i = tid; i < 2 * WG; i += 512){
    int hh = i / WG; int w = i - hh * WG;
    int h = h0 + hh;
    float2 acc = make_float2(0.f, 0.f);
    #pragma unroll
    for (int cc = 0; cc < 8; cc++){
      cmac(acc, seg[hh][cc * LSTR + w], upk(csmb[((size_t)(cc * ZT + z)) * HW2 + (size_t)h * WG + w]));
    }
    float sg = ((h + w) & 1) ? -1.f : 1.f;
    gwarped[((size_t)(p * ZE + zz)) * HW2 + (size_t)h * WG + w] = pk(make_float2(acc.x * sg, acc.y * sg));
  }
}

// ---------------- gather-tiled warp adjoint + fused gradient update ----------------
#define TRG 8
#define HAG 8
__global__ __launch_bounds__(512) void k_warpadj_update(const unsigned* __restrict__ gw, const float* __restrict__ mvf,
                                                        const unsigned* __restrict__ gtv, const float* __restrict__ stdp,
                                                        float2* __restrict__ x,
                                                        uint4* __restrict__ fb, unsigned int* __restrict__ fbcnt){
  __shared__ float lt[TRG * WG * 2];   // 20480 B
  int tid = threadIdx.x;
  int bid = blockIdx.x;                    // pz*40 + tile
  int tile = bid % 40; int pz = bid / 40;
  int zz = pz % ZE, p = pz / ZE, z = zz + 1;
  int R = tile * TRG;
  for (int i = tid; i < TRG * WG * 2; i += 512) lt[i] = 0.f;
  __syncthreads();
  const float* mvy = mvf + ((size_t)(p * 2 + 0) * ZT + z) * HW2;
  const float* mvx = mvy + (size_t)ZT * HW2;
  const unsigned* g = gw + (size_t)pz * HW2;
  const size_t xbase = (size_t)(p * ZT + z) * HW2;
  int wlo = max(R - HAG, 0), whi = min(R + TRG + HAG, HG);
  int npx = (whi - wlo) * WG;
  int base0 = wlo * WG;
  int i = tid;
  float fy = 0.f, fx = 0.f; unsigned gvp = 0u;
  if (i < npx){ fy = mvy[base0 + i]; fx = mvx[base0 + i]; gvp = g[base0 + i]; }
  while (i < npx){
    int inx = i + 512;
    float fy2 = 0.f, fx2 = 0.f; unsigned gvp2 = 0u;
    if (inx < npx){ fy2 = mvy[base0 + inx]; fx2 = mvx[base0 + inx]; gvp2 = g[base0 + inx]; }
    int hh = i / WG; int w = i - hh * WG;
    int h = wlo + hh;
    float gy = fminf(fmaxf((float)h + fy, 0.f), 319.f);
    float gx = fminf(fmaxf((float)w + fx, 0.f), 319.f);
    int y0, x0, y1, x1; float w00, w01, w10, w11;
    corners(gy, gx, y0, x0, y1, x1, w00, w01, w10, w11);
    float2 gv = upk(gvp);
    bool owner = (h >= R) && (h < R + TRG);
    #define PROC(Y, XC, WT) { \
      int ry = (Y) - R; \
      if ((unsigned)ry < (unsigned)TRG){ \
        atomicAdd(&lt[(ry * WG + (XC)) * 2 + 0], gv.x * (WT)); \
        atomicAdd(&lt[(ry * WG + (XC)) * 2 + 1], gv.y * (WT)); \
      } else if (owner){ \
        int Ry = (Y) & ~(TRG - 1); \
        if (h < Ry - HAG || h >= Ry + TRG + HAG){ \
          unsigned slot = atomicAdd(fbcnt, 1u); \
          if (slot < FBCAP) fb[slot] = make_uint4((unsigned)(xbase + (size_t)(Y) * WG + (XC)), \
                                                  __float_as_uint(gv.x * (WT)), __float_as_uint(gv.y * (WT)), 0u); \
        } \
      } \
    }
    PROC(y0, x0, w00); PROC(y0, x1, w01); PROC(y1, x0, w10); PROC(y1, x1, w11);
    #undef PROC
    i = inx; fy = fy2; fx = fx2; gvp = gvp2;
  }
  __syncthreads();
  float s = stdp[0];
  const unsigned* gt = gtv + (size_t)pz * HW2;
  for (int i2 = tid; i2 < TRG * WG; i2 += 512){
    int yy = i2 / WG; int w = i2 - yy * WG;
    int hw = (R + yy) * WG + w;
    float2 xv = x[xbase + hw];
    float2 tv = upk(gt[hw]);
    xv.x -= GAMMA_C * lt[i2 * 2 + 0] + TAU_C * s * tv.x;
    xv.y -= GAMMA_C * lt[i2 * 2 + 1] + TAU_C * s * tv.y;
    x[xbase + hw] = xv;
  }
}

// apply rare out-of-halo contributions: x[idx] -= GAMMA * val
__global__ __launch_bounds__(256) void k_fixup(const uint4* __restrict__ fb, const unsigned int* __restrict__ fbcnt,
                                               float2* __restrict__ x){
  unsigned n = *fbcnt; if (n > FBCAP) n = FBCAP;
  for (unsigned i = blockIdx.x * 256 + threadIdx.x; i < n; i += gridDim.x * 256){
    uint4 e = fb[i];
    atomicAdd(&x[e.x].x, -GAMMA_C * __uint_as_float(e.y));
    atomicAdd(&x[e.x].y, -GAMMA_C * __uint_as_float(e.z));
  }
}

// ---------------- host ----------------
extern "C" void kernel_launch(void* const* d_in, const int* in_sizes, int n_in,
                              void* d_out, int out_size, void* d_ws, size_t ws_size,
                              hipStream_t stream) {
  const float2* kdata = (const float2*)d_in[0];
  const float*  traj  = (const float*) d_in[1];
  const float2* img0  = (const float2*)d_in[2];
  const float*  mvf   = (const float*) d_in[3];
  const float2* csm   = (const float2*)d_in[4];
  const float*  stdp  = (const float*) d_in[5];
  float2* x = (float2*)d_out;

  const size_t F_B  = (size_t)CHN * ZE * HW2 * 4;        // 19,660,800 (bf16-packed complex)
  const size_t W_B  = (size_t)PH * ZE * HW2 * 4;         //  9,830,400 (bf16)
  const size_t C_B  = (size_t)CHN * ZT * HW2 * 4;        // 26,214,400 (bf16 csm)
  const size_t E_B  = (size_t)PH * CHN * ZE * NKP * 8;   //  6,291,456
  const size_t FB_B = (size_t)FBCAP * 16;                //  2,097,152
  const size_t P_B  = (size_t)PH * NKP * 16;             //    262,144
  const size_t SORT_B = P_B + 4 * 8192;

  size_t need_big = 4 * F_B + 2 * W_B + C_B + E_B + 512 + FB_B + SORT_B;   // ~134 MB
  const int NP = (ws_size >= need_big) ? 4 : 1;

  char* cur = (char*)d_ws;
  unsigned* F     = (unsigned*)cur;  cur += (size_t)NP * F_B;  // fwd: transposed; bwd: normal (bf16)
  unsigned* warped= (unsigned*)cur;  cur += W_B;               // bf16; also holds gwarped
  float2* est     = (float2*)cur;    cur += E_B;
  unsigned* gtvb  = (unsigned*)cur;  cur += W_B;               // bf16
  unsigned* csmb  = (unsigned*)cur;  cur += C_B;               // bf16 csm
  unsigned int* dmax  = (unsigned int*)cur; cur += 128;
  unsigned int* fbcnt = (unsigned int*)cur; cur += 128;
  uint4* fb           = (uint4*)cur;        cur += FB_B;
  float4* permx       = (float4*)cur;       cur += P_B;
  unsigned* xhist     = (unsigned*)cur;     cur += 8192;
  unsigned* xcur      = (unsigned*)cur;     cur += 8192;
  unsigned* xbnd      = (unsigned*)cur;     cur += 8192;

  k_init<<<12800, 256, 0, stream>>>(img0, x, PH * ZT * HW2);
  k_pack_csm<<<25600, 256, 0, stream>>>(csm, csmb, CHN * ZT * HW2);
  // build x-sorted k-point list (traj constant across iterations)
  hipMemsetAsync(xhist, 0, 8192, stream);
  k_khist<<<64, 256, 0, stream>>>(traj, xhist);
  k_kscan<<<1, 64, 0, stream>>>(xhist, xcur, xbnd);
  k_kperm<<<64, 256, 0, stream>>>(traj, xcur, permx);

  for (int it = 0; it < 3; it++){
    k_warp_tv<<<9600, 256, 0, stream>>>(x, mvf, warped, gtvb, dmax, fbcnt);
    for (int p0 = 0; p0 < PH; p0 += NP){
      k_fft_row_fwd   <<<NP *  960, 512, 0, stream>>>(warped, csmb, F, p0);           // 16 rows/block
      k_fft_col_sample<<<NP *  960, 256, 0, stream>>>(F, permx, xbnd, est, dmax, p0); // 2 slices/block
    }
    for (int p0 = 0; p0 < PH; p0 += NP){
      k_fft_col_scatter<<<NP *  960, 256, 0, stream>>>(est, kdata, permx, xbnd, dmax, F, p0);
      k_fft_row_bwd    <<<NP *  960, 512, 0, stream>>>(F, csmb, warped, p0);          // 2 rows/block
    }
    k_warpadj_update<<<960, 512, 0, stream>>>(warped, mvf, gtvb, stdp, x, fb, fbcnt);
    k_fixup<<<16, 256, 0, stream>>>(fb, fbcnt, x);
  }
}